// Round 9
// baseline (2184.541 us; speedup 1.0000x reference)
//
#include <hip/hip_runtime.h>
#include <math.h>

#define D4 20736
#define ST 14    // k123 LDS row stride (c32), 112B
#define SST 168  // 12*ST: spectator stride for bs23
#define KP 18    // k01 LDS row stride (c32), 144B

typedef float2 c32;

__device__ __forceinline__ c32 cmul(c32 a, c32 b) {
  return make_float2(a.x * b.x - a.y * b.y, a.x * b.y + a.y * b.x);
}
__device__ __forceinline__ c32 cfma(c32 a, c32 b, c32 acc) {
  acc.x = fmaf(a.x, b.x, fmaf(-a.y, b.y, acc.x));
  acc.y = fmaf(a.x, b.y, fmaf(a.y, b.x, acc.y));
  return acc;
}
__device__ __forceinline__ c32 get2(const float4* w, int n) {
  float4 q = w[n >> 1];
  return (n & 1) ? make_float2(q.z, q.w) : make_float2(q.x, q.y);
}
__device__ __forceinline__ float4 pack2(c32 a, c32 b) {
  return make_float4(a.x, a.y, b.x, b.y);
}
#define CZERO make_float2(0.f, 0.f)

// sector offsets: secoff[N] = sum_{n<N} sz(n)^2
__constant__ int d_secoff[24] = {0,1,5,14,30,55,91,140,204,285,385,506,650,
                                 771,871,952,1016,1065,1101,1126,1142,1151,1155,1156};

struct RM { int goff, sz, a0, da, r0, dr; };
// metadata for output pattern-row r=(i,j); a-walk in ST-flat units (bs23),
// r-walk in row units. Down-sectors iterate descending (gates column-reversed).
__device__ __forceinline__ RM rmeta(int r) {
  const int i = r / 12, j = r - 12 * i, N = i + j;
  const bool up = (N <= 11);
  RM m;
  m.sz = (up ? N : 22 - N) + 1;
  const int lo = up ? 0 : (N - 11);
  m.goff = d_secoff[N] + (i - lo) * m.sz;
  m.a0 = up ? N : (143 + N);
  m.da = up ? 13 : -13;
  m.r0 = up ? N : (121 + N);
  m.dr = up ? 11 : -11;
  return m;
}

// ---------------- small matrix expm (LDS, 64-thread block) ----------------
__device__ void small_expm(c32* A, c32* S, c32* P, c32* T, float* red, int sz, int tid) {
  const int n2 = sz * sz;
  if (tid < sz) {
    float s = 0.f;
    for (int j = 0; j < sz; ++j) { c32 v = A[tid * sz + j]; s += sqrtf(fmaf(v.x, v.x, v.y * v.y)); }
    red[tid] = s;
  }
  __syncthreads();
  float nrm = 0.f;
  for (int i = 0; i < sz; ++i) nrm = fmaxf(nrm, red[i]);
  int sp = 0;
  while (nrm > 0.35f && sp < 24) { nrm *= 0.5f; ++sp; }
  const float scale = ldexpf(1.f, -sp);
  for (int e = tid; e < n2; e += 64) { A[e].x *= scale; A[e].y *= scale; }
  __syncthreads();
  for (int e = tid; e < n2; e += 64) {
    c32 a = A[e];
    P[e] = a;
    if ((e / sz) == (e % sz)) a.x += 1.f;
    S[e] = a;
  }
  __syncthreads();
  for (int k = 2; k <= 12; ++k) {
    const float inv = 1.f / (float)k;
    for (int e = tid; e < n2; e += 64) {
      int i = e / sz, j = e - i * sz;
      c32 acc = CZERO;
      for (int q = 0; q < sz; ++q) acc = cfma(P[i * sz + q], A[q * sz + j], acc);
      acc.x *= inv; acc.y *= inv;
      T[e] = acc;
    }
    __syncthreads();
    for (int e = tid; e < n2; e += 64) {
      c32 t = T[e];
      P[e] = t;
      S[e].x += t.x; S[e].y += t.y;
    }
    __syncthreads();
  }
  for (int q = 0; q < sp; ++q) {
    for (int e = tid; e < n2; e += 64) {
      int i = e / sz, j = e - i * sz;
      c32 acc = CZERO;
      for (int w = 0; w < sz; ++w) acc = cfma(S[i * sz + w], S[w * sz + j], acc);
      T[e] = acc;
    }
    __syncthreads();
    for (int e = tid; e < n2; e += 64) S[e] = T[e];
    __syncthreads();
  }
}

// ---------------- prep: per-batch displacement encoding (store col 0) ----------------
__global__ __launch_bounds__(64) void prep_disp(const float* __restrict__ x, c32* __restrict__ c0) {
  __shared__ c32 A[144], S[144], P[144], T[144];
  __shared__ float red[12];
  const int tid = threadIdx.x;
  const int b = blockIdx.x >> 2, m = blockIdx.x & 3;
  const float rr = x[b * 8 + m], ph = x[b * 8 + 4 + m];
  float sn, cs;
  sincosf(ph, &sn, &cs);
  const c32 alpha = make_float2(rr * cs, rr * sn);
  for (int e = tid; e < 144; e += 64) A[e] = CZERO;
  __syncthreads();
  if (tid < 11) {
    float sq = sqrtf((float)(tid + 1));
    A[(tid + 1) * 12 + tid] = make_float2(alpha.x * sq, alpha.y * sq);
    A[tid * 12 + tid + 1] = make_float2(-alpha.x * sq, alpha.y * sq);
  }
  __syncthreads();
  small_expm(A, S, P, T, red, 12, tid);
  if (tid < 12) c0[(size_t)blockIdx.x * 12 + tid] = S[tid * 12];
}

// ---------------- prep: beamsplitter sector blocks (direction-arranged) ----------------
__global__ __launch_bounds__(64) void prep_bs(const float* __restrict__ th1, const float* __restrict__ ph1,
                                              const float* __restrict__ th2, const float* __restrict__ ph2,
                                              c32* __restrict__ BS) {
  __shared__ c32 A[144], S[144], P[144], T[144];
  __shared__ float red[12];
  const int tid = threadIdx.x;
  const int g = blockIdx.x / 23, N = blockIdx.x % 23;
  const int l = g / 12, rem = g % 12, w = rem / 6, gi = rem % 6;
  const float th = (w ? th2 : th1)[l * 6 + gi];
  const float ph = (w ? ph2 : ph1)[l * 6 + gi];
  const int lo = (N > 11) ? (N - 11) : 0;
  const int sz = (N <= 11) ? (N + 1) : (23 - N);
  float sn, cs;
  sincosf(ph, &sn, &cs);
  for (int e = tid; e < sz * sz; e += 64) A[e] = CZERO;
  __syncthreads();
  if (tid + 1 < sz) {
    int t = tid + 1;
    float s1 = th * sqrtf((float)((lo + t) * (N - lo - t + 1)));
    A[(t - 1) * sz + t] = make_float2(cs * s1, sn * s1);
    A[t * sz + t - 1] = make_float2(-cs * s1, sn * s1);
  }
  __syncthreads();
  small_expm(A, S, P, T, red, sz, tid);
  c32* dst = BS + (size_t)g * 1156 + d_secoff[N];
  const bool upSec = (N <= 11);
  for (int e = tid; e < sz * sz; e += 64) {
    int p = e / sz, q = e - p * sz;
    int qs = upSec ? q : (sz - 1 - q);
    dst[p * sz + q] = S[p * sz + qs];
  }
}

// ---------------- prep: per-mode composites P1 = S*R1, P2 = K*Disp*R2 ----------------
__global__ __launch_bounds__(64) void prep_p(const float* __restrict__ r_, const float* __restrict__ phir,
                                             const float* __restrict__ vphi1,
                                             const float* __restrict__ a_, const float* __restrict__ phia,
                                             const float* __restrict__ vphi2, const float* __restrict__ kk,
                                             c32* __restrict__ P1, c32* __restrict__ P2) {
  __shared__ c32 A[144], S[144], P[144], T[144];
  __shared__ float red[12];
  const int tid = threadIdx.x;
  const int which = blockIdx.x >> 3, lm = blockIdx.x & 7;
  for (int e = tid; e < 144; e += 64) A[e] = CZERO;
  __syncthreads();
  if (which == 0) {
    const float rv = r_[lm], pv = phir[lm];
    float sn, cs;
    sincosf(pv, &sn, &cs);
    const c32 z = make_float2(rv * cs, rv * sn);
    if (tid < 10) {
      float sq = 0.5f * sqrtf((float)((tid + 1) * (tid + 2)));
      A[tid * 12 + tid + 2] = make_float2(z.x * sq, -z.y * sq);
      A[(tid + 2) * 12 + tid] = make_float2(-z.x * sq, -z.y * sq);
    }
  } else {
    const float av = a_[lm], pv = phia[lm];
    float sn, cs;
    sincosf(pv, &sn, &cs);
    const c32 alpha = make_float2(av * cs, av * sn);
    if (tid < 11) {
      float sq = sqrtf((float)(tid + 1));
      A[(tid + 1) * 12 + tid] = make_float2(alpha.x * sq, alpha.y * sq);
      A[tid * 12 + tid + 1] = make_float2(-alpha.x * sq, alpha.y * sq);
    }
  }
  __syncthreads();
  small_expm(A, S, P, T, red, 12, tid);
  if (which == 0) {
    const float vp = vphi1[lm];
    for (int e = tid; e < 144; e += 64) {
      int j = e % 12;
      float sn, cs;
      sincosf(vp * (float)j, &sn, &cs);
      P1[(size_t)lm * 144 + e] = cmul(S[e], make_float2(cs, sn));
    }
  } else {
    const float vp = vphi2[lm], kv = kk[lm];
    for (int e = tid; e < 144; e += 64) {
      int i = e / 12, j = e % 12;
      float sn1, cs1, sn2, cs2;
      sincosf(vp * (float)j, &sn1, &cs1);
      float ang = kv * (float)i;
      ang *= (float)i;
      sincosf(ang, &sn2, &cs2);
      P2[(size_t)lm * 144 + e] = cmul(make_float2(cs2, sn2), cmul(S[e], make_float2(cs1, sn1)));
    }
  }
}

// ---------------- fused pass over modes {1,2,3}: BS(2,3) -> BS(1,2) -> U1 -> U2 -> U3 ----------------
// Slab (b,n0) of 1728 c32; single in-place LDS buffer [144 rows][14].
// Each pass: compute-to-regs -> sync -> write-back -> sync.  5 blocks/CU.
__global__ __launch_bounds__(256, 5) void k123_kernel(
    c32* __restrict__ psi,
    const c32* __restrict__ gbs23, const c32* __restrict__ gbs12,
    const c32* __restrict__ gu1, const c32* __restrict__ gu2, const c32* __restrict__ gu3) {
  __shared__ __align__(16) c32 buf[2016];
  __shared__ c32 gate[1168];
  __shared__ c32 gV1[144], gV2[144], gV3[144];
  const int tid = threadIdx.x;
  if (gu1) for (int e = tid; e < 144; e += 256) gV1[e] = gu1[e];
  if (gu2) for (int e = tid; e < 144; e += 256) gV2[e] = gu2[e];
  if (gu3) for (int e = tid; e < 144; e += 256) gV3[e] = gu3[e];
  for (int e = tid; e < 1156; e += 256) gate[e] = gbs23[e];
  c32* slab = psi + (size_t)blockIdx.x * 1728;
  for (int v = tid; v < 864; v += 256) {
    float4 q = ((const float4*)slab)[v];
    *((float4*)buf + 7 * (v / 6) + (v % 6)) = q;
  }
  __syncthreads();
  const int r = tid;
  RM m;
  if (r < 144) m = rmeta(r);
  c32 acc[12];
  // ---- pass 1: BS(2,3): pattern (n2,n3) within each 168-stride n1-block
  if (r < 144) {
#pragma unroll
    for (int n = 0; n < 12; ++n) acc[n] = CZERO;
    int a = m.a0;
#pragma unroll
    for (int t = 0; t < 12; ++t) {
      c32 g = gate[m.goff + t];
      if (t >= m.sz) g = CZERO;
#pragma unroll
      for (int n = 0; n < 12; ++n) acc[n] = cfma(g, buf[SST * n + a], acc[n]);
      a += m.da;
    }
  }
  __syncthreads();
  if (r < 144) {
    const int wr = ST * (r / 12) + (r % 12);
#pragma unroll
    for (int n = 0; n < 12; ++n) buf[SST * n + wr] = acc[n];
  }
  for (int e = tid; e < 1156; e += 256) gate[e] = gbs12[e];  // reload during write phase
  __syncthreads();
  // ---- pass 2: BS(1,2): pattern rows (n1,n2), spectator n3 in-row (b128)
  if (r < 144) {
#pragma unroll
    for (int n = 0; n < 12; ++n) acc[n] = CZERO;
    int rho = m.r0;
#pragma unroll
    for (int t = 0; t < 12; ++t) {
      c32 g = gate[m.goff + t];
      if (t >= m.sz) g = CZERO;
      const float4* ip = (const float4*)buf + 7 * rho;
      float4 w[6];
#pragma unroll
      for (int q = 0; q < 6; ++q) w[q] = ip[q];
#pragma unroll
      for (int n = 0; n < 12; ++n) acc[n] = cfma(g, get2(w, n), acc[n]);
      rho += m.dr;
    }
  }
  __syncthreads();
  if (r < 144) {
    float4* op = (float4*)buf + 7 * r;
#pragma unroll
    for (int q = 0; q < 6; ++q) op[q] = pack2(acc[2 * q], acc[2 * q + 1]);
  }
  // ---- U1 on n1: out row 12i+n2 reads rows 12j+n2
  if (gu1) {
    __syncthreads();
    if (r < 144) {
      const int i = r / 12, n2 = r - 12 * (r / 12);
#pragma unroll
      for (int n = 0; n < 12; ++n) acc[n] = CZERO;
#pragma unroll
      for (int j = 0; j < 12; ++j) {
        c32 g = gV1[i * 12 + j];
        const float4* ip = (const float4*)buf + 7 * (12 * j + n2);
        float4 w[6];
#pragma unroll
        for (int q = 0; q < 6; ++q) w[q] = ip[q];
#pragma unroll
        for (int n = 0; n < 12; ++n) acc[n] = cfma(g, get2(w, n), acc[n]);
      }
    }
    __syncthreads();
    if (r < 144) {
      float4* op = (float4*)buf + 7 * r;
#pragma unroll
      for (int q = 0; q < 6; ++q) op[q] = pack2(acc[2 * q], acc[2 * q + 1]);
    }
  }
  // ---- U2 on n2: out row 12n1+i reads rows 12n1+j
  if (gu2) {
    __syncthreads();
    if (r < 144) {
      const int n1 = r / 12, i = r - 12 * (r / 12);
#pragma unroll
      for (int n = 0; n < 12; ++n) acc[n] = CZERO;
#pragma unroll
      for (int j = 0; j < 12; ++j) {
        c32 g = gV2[i * 12 + j];
        const float4* ip = (const float4*)buf + 7 * (12 * n1 + j);
        float4 w[6];
#pragma unroll
        for (int q = 0; q < 6; ++q) w[q] = ip[q];
#pragma unroll
        for (int n = 0; n < 12; ++n) acc[n] = cfma(g, get2(w, n), acc[n]);
      }
    }
    __syncthreads();
    if (r < 144) {
      float4* op = (float4*)buf + 7 * r;
#pragma unroll
      for (int q = 0; q < 6; ++q) op[q] = pack2(acc[2 * q], acc[2 * q + 1]);
    }
  }
  // ---- U3 on n3: purely in-row (thread owns its row; no cross-thread hazard)
  if (gu3) {
    __syncthreads();
    if (r < 144) {
      const float4* ip = (const float4*)buf + 7 * r;
      float4 wv[6];
#pragma unroll
      for (int q = 0; q < 6; ++q) wv[q] = ip[q];
      float4* op = (float4*)buf + 7 * r;
#pragma unroll
      for (int cpair = 0; cpair < 6; ++cpair) {
        c32 s0 = CZERO, s1 = CZERO;
#pragma unroll
        for (int j = 0; j < 12; ++j) {
          c32 v = get2(wv, j);
          s0 = cfma(gV3[(2 * cpair) * 12 + j], v, s0);
          s1 = cfma(gV3[(2 * cpair + 1) * 12 + j], v, s1);
        }
        op[cpair] = pack2(s0, s1);
      }
    }
  }
  __syncthreads();
  for (int v = tid; v < 864; v += 256) {
    ((float4*)slab)[v] = *((const float4*)buf + 7 * (v / 6) + (v % 6));
  }
}

// ---------------- fused pass over modes {0,1}: [init] -> U0 -> BS(0,1) ----------------
// Tile = 144 (n0,n1)-rows x 16 flat cols; single in-place LDS [144][18]. 5 blocks/CU.
__global__ __launch_bounds__(256, 5) void k01_kernel(
    c32* __restrict__ psi, const c32* __restrict__ c0,
    const c32* __restrict__ gu0, const c32* __restrict__ gbs) {
  __shared__ __align__(16) c32 buf[2592];
  __shared__ c32 gate[1168];
  __shared__ c32 g0v[144];
  __shared__ c32 cv[4][12];
  const int tid = threadIdx.x;
  const int b = blockIdx.x / 9, t = blockIdx.x % 9;
  if (gu0) for (int e = tid; e < 144; e += 256) g0v[e] = gu0[e];
  if (gbs) for (int e = tid; e < 1156; e += 256) gate[e] = gbs[e];
  c32* gbase = psi + (size_t)b * D4 + t * 16;
  if (c0) {
    if (tid < 48) cv[tid / 12][tid % 12] = c0[(size_t)b * 48 + tid];
    __syncthreads();
    for (int e = tid; e < 2304; e += 256) {
      int row = e >> 4, q = e & 15;
      int cc = 16 * t + q, n2 = cc / 12, n3 = cc - 12 * n2;
      buf[KP * row + q] =
          cmul(cmul(cv[0][row / 12], cv[1][row % 12]), cmul(cv[2][n2], cv[3][n3]));
    }
  } else {
    for (int e = tid; e < 1152; e += 256) {
      int row = e >> 3, q = e & 7;
      ((float4*)(buf + row * KP))[q] = ((const float4*)(gbase + (size_t)row * 144))[q];
    }
  }
  __syncthreads();
  const int r = tid;
  c32 acc[16];
  // ---- U0 on n0: out row 12i+n1 reads rows 12j+n1
  if (gu0) {
    if (r < 144) {
      const int i = r / 12, n1 = r - 12 * (r / 12);
#pragma unroll
      for (int n = 0; n < 16; ++n) acc[n] = CZERO;
#pragma unroll
      for (int j = 0; j < 12; ++j) {
        c32 g = g0v[i * 12 + j];
        const float4* ip = (const float4*)(buf + (12 * j + n1) * KP);
        float4 w[8];
#pragma unroll
        for (int q = 0; q < 8; ++q) w[q] = ip[q];
#pragma unroll
        for (int n = 0; n < 16; ++n) acc[n] = cfma(g, get2(w, n), acc[n]);
      }
    }
    __syncthreads();
    if (r < 144) {
      float4* op = (float4*)(buf + r * KP);
#pragma unroll
      for (int q = 0; q < 8; ++q) op[q] = pack2(acc[2 * q], acc[2 * q + 1]);
    }
    __syncthreads();
  }
  // ---- BS(0,1): pattern rows (n0,n1)
  if (gbs) {
    if (r < 144) {
      const RM m = rmeta(r);
#pragma unroll
      for (int n = 0; n < 16; ++n) acc[n] = CZERO;
      int rho = m.r0;
#pragma unroll
      for (int tk = 0; tk < 12; ++tk) {
        c32 g = gate[m.goff + tk];
        if (tk >= m.sz) g = CZERO;
        const float4* ip = (const float4*)(buf + rho * KP);
        float4 w[8];
#pragma unroll
        for (int q = 0; q < 8; ++q) w[q] = ip[q];
#pragma unroll
        for (int n = 0; n < 16; ++n) acc[n] = cfma(g, get2(w, n), acc[n]);
        rho += m.dr;
      }
    }
    __syncthreads();
    if (r < 144) {
      float4* op = (float4*)(buf + r * KP);
#pragma unroll
      for (int q = 0; q < 8; ++q) op[q] = pack2(acc[2 * q], acc[2 * q + 1]);
    }
    __syncthreads();
  }
  for (int e = tid; e < 1152; e += 256) {
    int row = e >> 3, q = e & 7;
    ((float4*)(gbase + (size_t)row * 144))[q] = ((const float4*)(buf + row * KP))[q];
  }
}

// ---------------- expvals: <X_m> = sum 2*sqrt(n+1)*Re(conj(psi_n) psi_{n+1}) ----------------
__global__ __launch_bounds__(256) void expval_kernel(const c32* __restrict__ psi, float* __restrict__ out) {
  __shared__ float red[1024];
  __shared__ float sq2[12];
  const int tid = threadIdx.x, b = blockIdx.x;
  if (tid < 12) sq2[tid] = 2.f * sqrtf((float)(tid + 1));
  __syncthreads();
  const c32* base = psi + (size_t)b * D4;
  float a0 = 0.f, a1 = 0.f, a2 = 0.f, a3 = 0.f;
  for (int e = tid; e < D4; e += 256) {
    c32 p = base[e];
    int n3 = e % 12, t = e / 12;
    int n2 = t % 12; t /= 12;
    int n1 = t % 12, n0 = t / 12;
    if (n3 < 11) { c32 q = base[e + 1];    a3 = fmaf(sq2[n3], fmaf(p.x, q.x, p.y * q.y), a3); }
    if (n2 < 11) { c32 q = base[e + 12];   a2 = fmaf(sq2[n2], fmaf(p.x, q.x, p.y * q.y), a2); }
    if (n1 < 11) { c32 q = base[e + 144];  a1 = fmaf(sq2[n1], fmaf(p.x, q.x, p.y * q.y), a1); }
    if (n0 < 11) { c32 q = base[e + 1728]; a0 = fmaf(sq2[n0], fmaf(p.x, q.x, p.y * q.y), a0); }
  }
  red[tid * 4 + 0] = a0; red[tid * 4 + 1] = a1; red[tid * 4 + 2] = a2; red[tid * 4 + 3] = a3;
  __syncthreads();
  for (int s = 128; s > 0; s >>= 1) {
    if (tid < s) {
      red[tid * 4 + 0] += red[(tid + s) * 4 + 0];
      red[tid * 4 + 1] += red[(tid + s) * 4 + 1];
      red[tid * 4 + 2] += red[(tid + s) * 4 + 2];
      red[tid * 4 + 3] += red[(tid + s) * 4 + 3];
    }
    __syncthreads();
  }
  if (tid < 4) out[b * 4 + tid] = red[tid];
}

extern "C" void kernel_launch(void* const* d_in, const int* in_sizes, int n_in,
                              void* d_out, int out_size, void* d_ws, size_t ws_size,
                              hipStream_t stream) {
  const float* x      = (const float*)d_in[0];
  const float* theta1 = (const float*)d_in[1];
  const float* phi1   = (const float*)d_in[2];
  const float* vphi1  = (const float*)d_in[3];
  const float* r_     = (const float*)d_in[4];
  const float* phir   = (const float*)d_in[5];
  const float* theta2 = (const float*)d_in[6];
  const float* phi2   = (const float*)d_in[7];
  const float* vphi2  = (const float*)d_in[8];
  const float* a_     = (const float*)d_in[9];
  const float* phia   = (const float*)d_in[10];
  const float* kk     = (const float*)d_in[11];
  float* out = (float*)d_out;

  // workspace layout (bytes)
  const size_t PSI_OFF = 0;                              // 1024*20736*8
  const size_t C0_OFF  = 169869312;                      // 1024*4*12*8
  const size_t P1_OFF  = C0_OFF + 393216;
  const size_t P2_OFF  = P1_OFF + 9216;
  const size_t BS_OFF  = P2_OFF + 9216;                  // 24*1156*8
  const size_t NEED    = BS_OFF + 221952;
  if (ws_size < NEED) return;

  char* ws = (char*)d_ws;
  c32* psi = (c32*)(ws + PSI_OFF);
  c32* c0  = (c32*)(ws + C0_OFF);
  c32* P1  = (c32*)(ws + P1_OFF);
  c32* P2  = (c32*)(ws + P2_OFF);
  c32* BS  = (c32*)(ws + BS_OFF);

  prep_disp<<<dim3(4096), dim3(64), 0, stream>>>(x, c0);
  prep_bs<<<dim3(552), dim3(64), 0, stream>>>(theta1, phi1, theta2, phi2, BS);
  prep_p<<<dim3(16), dim3(64), 0, stream>>>(r_, phir, vphi1, a_, phia, vphi2, kk, P1, P2);

  for (int l = 0; l < 2; ++l) {
    c32* bsl = BS + (size_t)l * 12 * 1156;
    const c32* c0arg = (l == 0) ? c0 : (const c32*)nullptr;
    const c32* u0pre = (l == 0) ? (const c32*)nullptr : (const c32*)(P2 + (size_t)(l - 1) * 4 * 144);
    // interferometer 1: Clements order (0,1),(2,3),(1,2),(0,1),(2,3),(1,2)
    k01_kernel<<<dim3(9216), dim3(256), 0, stream>>>(psi, c0arg, u0pre, bsl + 0 * 1156);
    k123_kernel<<<dim3(12288), dim3(256), 0, stream>>>(psi, bsl + 1 * 1156, bsl + 2 * 1156,
                                                       nullptr, nullptr, nullptr);
    k01_kernel<<<dim3(9216), dim3(256), 0, stream>>>(psi, nullptr, nullptr, bsl + 3 * 1156);
    k123_kernel<<<dim3(12288), dim3(256), 0, stream>>>(psi, bsl + 4 * 1156, bsl + 5 * 1156,
                                                       P1 + (size_t)(l * 4 + 1) * 144,
                                                       P1 + (size_t)(l * 4 + 2) * 144,
                                                       P1 + (size_t)(l * 4 + 3) * 144);
    // interferometer 2 (P1 mode-0 composite rides along before its first BS(0,1))
    k01_kernel<<<dim3(9216), dim3(256), 0, stream>>>(psi, nullptr, P1 + (size_t)(l * 4 + 0) * 144, bsl + 6 * 1156);
    k123_kernel<<<dim3(12288), dim3(256), 0, stream>>>(psi, bsl + 7 * 1156, bsl + 8 * 1156,
                                                       nullptr, nullptr, nullptr);
    k01_kernel<<<dim3(9216), dim3(256), 0, stream>>>(psi, nullptr, nullptr, bsl + 9 * 1156);
    k123_kernel<<<dim3(12288), dim3(256), 0, stream>>>(psi, bsl + 10 * 1156, bsl + 11 * 1156,
                                                       P2 + (size_t)(l * 4 + 1) * 144,
                                                       P2 + (size_t)(l * 4 + 2) * 144,
                                                       P2 + (size_t)(l * 4 + 3) * 144);
  }
  // final pending mode-0 composite from layer 2
  k01_kernel<<<dim3(9216), dim3(256), 0, stream>>>(psi, nullptr, P2 + (size_t)(1 * 4 + 0) * 144, nullptr);
  expval_kernel<<<dim3(1024), dim3(256), 0, stream>>>(psi, out);
}

// Round 10
// 2059.008 us; speedup vs baseline: 1.0610x; 1.0610x over previous
//
#include <hip/hip_runtime.h>
#include <math.h>

#define D4 20736
#define ST 14    // k123 LDS row stride (c32), 112B; cols 12,13 = pad storage for gV1/gV2
#define SST 168  // 12*ST: spectator stride for bs23
#define KP 18    // k01 LDS row stride (c32), 144B; cols 16,17 = pad storage for g0v

typedef float2 c32;

__device__ __forceinline__ c32 cmul(c32 a, c32 b) {
  return make_float2(a.x * b.x - a.y * b.y, a.x * b.y + a.y * b.x);
}
__device__ __forceinline__ c32 cfma(c32 a, c32 b, c32 acc) {
  acc.x = fmaf(a.x, b.x, fmaf(-a.y, b.y, acc.x));
  acc.y = fmaf(a.x, b.y, fmaf(a.y, b.x, acc.y));
  return acc;
}
__device__ __forceinline__ c32 get2(const float4* w, int n) {
  float4 q = w[n >> 1];
  return (n & 1) ? make_float2(q.z, q.w) : make_float2(q.x, q.y);
}
__device__ __forceinline__ float4 pack2(c32 a, c32 b) {
  return make_float4(a.x, a.y, b.x, b.y);
}
#define CZERO make_float2(0.f, 0.f)

// sector offsets: secoff[N] = sum_{n<N} sz(n)^2
__constant__ int d_secoff[24] = {0,1,5,14,30,55,91,140,204,285,385,506,650,
                                 771,871,952,1016,1065,1101,1126,1142,1151,1155,1156};

// rows sorted by descending sector size -> per-wave loop-trip maxima 12/9/4
__constant__ unsigned char d_perm[144] = {
  11,22,33,44,55,66,77,88,99,110,121,132,      // N=11 sz12
  10,21,32,43,54,65,76,87,98,109,120,          // N=10 sz11
  23,34,45,56,67,78,89,100,111,122,133,        // N=12 sz11
  9,20,31,42,53,64,75,86,97,108,               // N=9  sz10
  35,46,57,68,79,90,101,112,123,134,           // N=13 sz10
  8,19,30,41,52,63,74,85,96,                   // N=8  sz9
  47,58,69,80,91,102,113,124,135,              // N=14 sz9
  7,18,29,40,51,62,73,84,                      // N=7  sz8
  59,70,81,92,103,114,125,136,                 // N=15 sz8
  6,17,28,39,50,61,72,                         // N=6  sz7
  71,82,93,104,115,126,137,                    // N=16 sz7
  5,16,27,38,49,60,                            // N=5  sz6
  83,94,105,116,127,138,                       // N=17 sz6
  4,15,26,37,48,                               // N=4  sz5
  95,106,117,128,139,                          // N=18 sz5
  3,14,25,36,                                  // N=3  sz4
  107,118,129,140,                             // N=19 sz4
  2,13,24,                                     // N=2  sz3
  119,130,141,                                 // N=20 sz3
  1,12,                                        // N=1  sz2
  131,142,                                     // N=21 sz2
  0,                                           // N=0  sz1
  143                                          // N=22 sz1
};

struct RM { int goff, sz, a0, da, r0, dr; };
// metadata for output pattern-row r=(i,j). Gates stored TRANSPOSED per sector:
// element (p=i-lo, walk-step t) at secoff + t*sz + p  -> per-iteration lane
// reads are consecutive (conflict-free). goff walks += sz per iteration.
// Down-sectors iterate descending (prep_bs stores column-reversed).
__device__ __forceinline__ RM rmeta(int r) {
  const int i = r / 12, j = r - 12 * i, N = i + j;
  const bool up = (N <= 11);
  RM m;
  m.sz = (up ? N : 22 - N) + 1;
  const int lo = up ? 0 : (N - 11);
  m.goff = d_secoff[N] + (i - lo);
  m.a0 = up ? N : (143 + N);
  m.da = up ? 13 : -13;
  m.r0 = up ? N : (121 + N);
  m.dr = up ? 11 : -11;
  return m;
}

// ---------------- small matrix expm (LDS, 64-thread block) ----------------
__device__ void small_expm(c32* A, c32* S, c32* P, c32* T, float* red, int sz, int tid) {
  const int n2 = sz * sz;
  if (tid < sz) {
    float s = 0.f;
    for (int j = 0; j < sz; ++j) { c32 v = A[tid * sz + j]; s += sqrtf(fmaf(v.x, v.x, v.y * v.y)); }
    red[tid] = s;
  }
  __syncthreads();
  float nrm = 0.f;
  for (int i = 0; i < sz; ++i) nrm = fmaxf(nrm, red[i]);
  int sp = 0;
  while (nrm > 0.35f && sp < 24) { nrm *= 0.5f; ++sp; }
  const float scale = ldexpf(1.f, -sp);
  for (int e = tid; e < n2; e += 64) { A[e].x *= scale; A[e].y *= scale; }
  __syncthreads();
  for (int e = tid; e < n2; e += 64) {
    c32 a = A[e];
    P[e] = a;
    if ((e / sz) == (e % sz)) a.x += 1.f;
    S[e] = a;
  }
  __syncthreads();
  for (int k = 2; k <= 12; ++k) {
    const float inv = 1.f / (float)k;
    for (int e = tid; e < n2; e += 64) {
      int i = e / sz, j = e - i * sz;
      c32 acc = CZERO;
      for (int q = 0; q < sz; ++q) acc = cfma(P[i * sz + q], A[q * sz + j], acc);
      acc.x *= inv; acc.y *= inv;
      T[e] = acc;
    }
    __syncthreads();
    for (int e = tid; e < n2; e += 64) {
      c32 t = T[e];
      P[e] = t;
      S[e].x += t.x; S[e].y += t.y;
    }
    __syncthreads();
  }
  for (int q = 0; q < sp; ++q) {
    for (int e = tid; e < n2; e += 64) {
      int i = e / sz, j = e - i * sz;
      c32 acc = CZERO;
      for (int w = 0; w < sz; ++w) acc = cfma(S[i * sz + w], S[w * sz + j], acc);
      T[e] = acc;
    }
    __syncthreads();
    for (int e = tid; e < n2; e += 64) S[e] = T[e];
    __syncthreads();
  }
}

// ---------------- prep: per-batch displacement encoding (store col 0) ----------------
__global__ __launch_bounds__(64) void prep_disp(const float* __restrict__ x, c32* __restrict__ c0) {
  __shared__ c32 A[144], S[144], P[144], T[144];
  __shared__ float red[12];
  const int tid = threadIdx.x;
  const int b = blockIdx.x >> 2, m = blockIdx.x & 3;
  const float rr = x[b * 8 + m], ph = x[b * 8 + 4 + m];
  float sn, cs;
  sincosf(ph, &sn, &cs);
  const c32 alpha = make_float2(rr * cs, rr * sn);
  for (int e = tid; e < 144; e += 64) A[e] = CZERO;
  __syncthreads();
  if (tid < 11) {
    float sq = sqrtf((float)(tid + 1));
    A[(tid + 1) * 12 + tid] = make_float2(alpha.x * sq, alpha.y * sq);
    A[tid * 12 + tid + 1] = make_float2(-alpha.x * sq, alpha.y * sq);
  }
  __syncthreads();
  small_expm(A, S, P, T, red, 12, tid);
  if (tid < 12) c0[(size_t)blockIdx.x * 12 + tid] = S[tid * 12];
}

// ---------------- prep: beamsplitter sector blocks (transposed, direction-arranged) ----------------
__global__ __launch_bounds__(64) void prep_bs(const float* __restrict__ th1, const float* __restrict__ ph1,
                                              const float* __restrict__ th2, const float* __restrict__ ph2,
                                              c32* __restrict__ BS) {
  __shared__ c32 A[144], S[144], P[144], T[144];
  __shared__ float red[12];
  const int tid = threadIdx.x;
  const int g = blockIdx.x / 23, N = blockIdx.x % 23;
  const int l = g / 12, rem = g % 12, w = rem / 6, gi = rem % 6;
  const float th = (w ? th2 : th1)[l * 6 + gi];
  const float ph = (w ? ph2 : ph1)[l * 6 + gi];
  const int lo = (N > 11) ? (N - 11) : 0;
  const int sz = (N <= 11) ? (N + 1) : (23 - N);
  float sn, cs;
  sincosf(ph, &sn, &cs);
  for (int e = tid; e < sz * sz; e += 64) A[e] = CZERO;
  __syncthreads();
  if (tid + 1 < sz) {
    int t = tid + 1;
    float s1 = th * sqrtf((float)((lo + t) * (N - lo - t + 1)));
    A[(t - 1) * sz + t] = make_float2(cs * s1, sn * s1);
    A[t * sz + t - 1] = make_float2(-cs * s1, sn * s1);
  }
  __syncthreads();
  small_expm(A, S, P, T, red, sz, tid);
  // store TRANSPOSED: (p, walk-step q) -> dst[q*sz + p]; down-sectors column-reversed
  c32* dst = BS + (size_t)g * 1156 + d_secoff[N];
  const bool upSec = (N <= 11);
  for (int e = tid; e < sz * sz; e += 64) {
    int p = e / sz, q = e - p * sz;
    int qs = upSec ? q : (sz - 1 - q);
    dst[q * sz + p] = S[p * sz + qs];
  }
}

// ---------------- prep: per-mode composites P1 = S*R1, P2 = K*Disp*R2 ----------------
__global__ __launch_bounds__(64) void prep_p(const float* __restrict__ r_, const float* __restrict__ phir,
                                             const float* __restrict__ vphi1,
                                             const float* __restrict__ a_, const float* __restrict__ phia,
                                             const float* __restrict__ vphi2, const float* __restrict__ kk,
                                             c32* __restrict__ P1, c32* __restrict__ P2) {
  __shared__ c32 A[144], S[144], P[144], T[144];
  __shared__ float red[12];
  const int tid = threadIdx.x;
  const int which = blockIdx.x >> 3, lm = blockIdx.x & 7;
  for (int e = tid; e < 144; e += 64) A[e] = CZERO;
  __syncthreads();
  if (which == 0) {
    const float rv = r_[lm], pv = phir[lm];
    float sn, cs;
    sincosf(pv, &sn, &cs);
    const c32 z = make_float2(rv * cs, rv * sn);
    if (tid < 10) {
      float sq = 0.5f * sqrtf((float)((tid + 1) * (tid + 2)));
      A[tid * 12 + tid + 2] = make_float2(z.x * sq, -z.y * sq);
      A[(tid + 2) * 12 + tid] = make_float2(-z.x * sq, -z.y * sq);
    }
  } else {
    const float av = a_[lm], pv = phia[lm];
    float sn, cs;
    sincosf(pv, &sn, &cs);
    const c32 alpha = make_float2(av * cs, av * sn);
    if (tid < 11) {
      float sq = sqrtf((float)(tid + 1));
      A[(tid + 1) * 12 + tid] = make_float2(alpha.x * sq, alpha.y * sq);
      A[tid * 12 + tid + 1] = make_float2(-alpha.x * sq, alpha.y * sq);
    }
  }
  __syncthreads();
  small_expm(A, S, P, T, red, 12, tid);
  if (which == 0) {
    const float vp = vphi1[lm];
    for (int e = tid; e < 144; e += 64) {
      int j = e % 12;
      float sn, cs;
      sincosf(vp * (float)j, &sn, &cs);
      P1[(size_t)lm * 144 + e] = cmul(S[e], make_float2(cs, sn));
    }
  } else {
    const float vp = vphi2[lm], kv = kk[lm];
    for (int e = tid; e < 144; e += 64) {
      int i = e / 12, j = e % 12;
      float sn1, cs1, sn2, cs2;
      sincosf(vp * (float)j, &sn1, &cs1);
      float ang = kv * (float)i;
      ang *= (float)i;
      sincosf(ang, &sn2, &cs2);
      P2[(size_t)lm * 144 + e] = cmul(make_float2(cs2, sn2), cmul(S[e], make_float2(cs1, sn1)));
    }
  }
}

// ---------------- fused pass over modes {1,2,3}: BS(2,3) -> BS(1,2) -> U1 -> U2 -> U3 ----------------
// Slab (b,n0) of 1728 c32; in-place LDS [144][14]; pads hold gV1/gV2; gate buffer
// reused bs23 -> bs12 (reg-prefetched) -> gV3. 6 blocks/CU.
__global__ __launch_bounds__(256, 6) void k123_kernel(
    c32* __restrict__ psi,
    const c32* __restrict__ gbs23, const c32* __restrict__ gbs12,
    const c32* __restrict__ gu1, const c32* __restrict__ gu2, const c32* __restrict__ gu3) {
  __shared__ __align__(16) c32 buf[2016];
  __shared__ c32 gate[1168];
  const int tid = threadIdx.x;
  // register prefetch: bs12 (stored to gate during pass-1 write phase) and gV3
  c32 pf[5];
#pragma unroll
  for (int k = 0; k < 5; ++k) {
    int e = tid + 256 * k;
    pf[k] = (e < 1156) ? gbs12[e] : CZERO;
  }
  c32 pf3 = (gu3 && tid < 144) ? gu3[tid] : CZERO;
  // gV1/gV2 into pad columns 12/13
  if (gu1) for (int e = tid; e < 144; e += 256) buf[ST * e + 12] = gu1[e];
  if (gu2) for (int e = tid; e < 144; e += 256) buf[ST * e + 13] = gu2[e];
  for (int e = tid; e < 1156; e += 256) gate[e] = gbs23[e];
  c32* slab = psi + (size_t)blockIdx.x * 1728;
  for (int v = tid; v < 864; v += 256) {
    float4 q = ((const float4*)slab)[v];
    *((float4*)buf + 7 * (v / 6) + (v % 6)) = q;
  }
  __syncthreads();
  const int rb = (tid < 144) ? (int)d_perm[tid] : 0;
  RM m;
  if (tid < 144) m = rmeta(rb);
  c32 acc[12];
  // ---- pass 1: BS(2,3): pattern (n2,n3) within each 168-stride n1-block
  if (tid < 144) {
#pragma unroll
    for (int n = 0; n < 12; ++n) acc[n] = CZERO;
    int a = m.a0, go = m.goff;
    for (int t = 0; t < m.sz; ++t) {
      c32 g = gate[go];
      go += m.sz;
#pragma unroll
      for (int n = 0; n < 12; ++n) acc[n] = cfma(g, buf[SST * n + a], acc[n]);
      a += m.da;
    }
  }
  __syncthreads();
  if (tid < 144) {
    const int wr = ST * (rb / 12) + (rb % 12);
#pragma unroll
    for (int n = 0; n < 12; ++n) buf[SST * n + wr] = acc[n];
  }
#pragma unroll
  for (int k = 0; k < 5; ++k) {  // bs12 from prefetch regs (no HBM latency here)
    int e = tid + 256 * k;
    if (e < 1156) gate[e] = pf[k];
  }
  __syncthreads();
  // ---- pass 2: BS(1,2): pattern rows (n1,n2), spectator n3 in-row (b128)
  if (tid < 144) {
#pragma unroll
    for (int n = 0; n < 12; ++n) acc[n] = CZERO;
    int rho = m.r0, go = m.goff;
    for (int t = 0; t < m.sz; ++t) {
      c32 g = gate[go];
      go += m.sz;
      const float4* ip = (const float4*)buf + 7 * rho;
      float4 w[6];
#pragma unroll
      for (int q = 0; q < 6; ++q) w[q] = ip[q];
#pragma unroll
      for (int n = 0; n < 12; ++n) acc[n] = cfma(g, get2(w, n), acc[n]);
      rho += m.dr;
    }
  }
  __syncthreads();
  if (tid < 144) {
    float4* op = (float4*)buf + 7 * rb;
#pragma unroll
    for (int q = 0; q < 6; ++q) op[q] = pack2(acc[2 * q], acc[2 * q + 1]);
  }
  if (gu3 && tid < 144) gate[tid] = pf3;  // gate buffer free now: stash gV3
  // ---- U1 on n1: out row 12i+n2 reads rows 12j+n2; gate from pad col 12
  if (gu1) {
    __syncthreads();
    if (tid < 144) {
      const int i = tid / 12, n2 = tid - 12 * (tid / 12);
#pragma unroll
      for (int n = 0; n < 12; ++n) acc[n] = CZERO;
#pragma unroll
      for (int j = 0; j < 12; ++j) {
        c32 g = buf[ST * (i * 12 + j) + 12];
        const float4* ip = (const float4*)buf + 7 * (12 * j + n2);
        float4 w[6];
#pragma unroll
        for (int q = 0; q < 6; ++q) w[q] = ip[q];
#pragma unroll
        for (int n = 0; n < 12; ++n) acc[n] = cfma(g, get2(w, n), acc[n]);
      }
    }
    __syncthreads();
    if (tid < 144) {
      float4* op = (float4*)buf + 7 * tid;
#pragma unroll
      for (int q = 0; q < 6; ++q) op[q] = pack2(acc[2 * q], acc[2 * q + 1]);
    }
  }
  // ---- U2 on n2: out row 12n1+i reads rows 12n1+j; gate from pad col 13
  if (gu2) {
    __syncthreads();
    if (tid < 144) {
      const int n1 = tid / 12, i = tid - 12 * (tid / 12);
#pragma unroll
      for (int n = 0; n < 12; ++n) acc[n] = CZERO;
#pragma unroll
      for (int j = 0; j < 12; ++j) {
        c32 g = buf[ST * (i * 12 + j) + 13];
        const float4* ip = (const float4*)buf + 7 * (12 * n1 + j);
        float4 w[6];
#pragma unroll
        for (int q = 0; q < 6; ++q) w[q] = ip[q];
#pragma unroll
        for (int n = 0; n < 12; ++n) acc[n] = cfma(g, get2(w, n), acc[n]);
      }
    }
    __syncthreads();
    if (tid < 144) {
      float4* op = (float4*)buf + 7 * tid;
#pragma unroll
      for (int q = 0; q < 6; ++q) op[q] = pack2(acc[2 * q], acc[2 * q + 1]);
    }
  }
  // ---- U3 on n3: in-row; gate stashed in gate[0..143]
  if (gu3) {
    __syncthreads();
    if (tid < 144) {
      const float4* ip = (const float4*)buf + 7 * tid;
      float4 wv[6];
#pragma unroll
      for (int q = 0; q < 6; ++q) wv[q] = ip[q];
      float4* op = (float4*)buf + 7 * tid;
#pragma unroll
      for (int cpair = 0; cpair < 6; ++cpair) {
        c32 s0 = CZERO, s1 = CZERO;
#pragma unroll
        for (int j = 0; j < 12; ++j) {
          c32 v = get2(wv, j);
          s0 = cfma(gate[(2 * cpair) * 12 + j], v, s0);
          s1 = cfma(gate[(2 * cpair + 1) * 12 + j], v, s1);
        }
        op[cpair] = pack2(s0, s1);
      }
    }
  }
  __syncthreads();
  for (int v = tid; v < 864; v += 256) {
    ((float4*)slab)[v] = *((const float4*)buf + 7 * (v / 6) + (v % 6));
  }
}

// ---------------- fused pass over modes {0,1}: [init] -> U0 -> BS(0,1) ----------------
// Tile = 144 (n0,n1)-rows x 16 flat cols; in-place LDS [144][18]; pad col 16 = g0v.
__global__ __launch_bounds__(256, 5) void k01_kernel(
    c32* __restrict__ psi, const c32* __restrict__ c0,
    const c32* __restrict__ gu0, const c32* __restrict__ gbs) {
  __shared__ __align__(16) c32 buf[2592];
  __shared__ c32 gate[1168];
  __shared__ c32 cv[4][12];
  const int tid = threadIdx.x;
  const int b = blockIdx.x / 9, t = blockIdx.x % 9;
  if (gu0) for (int e = tid; e < 144; e += 256) buf[KP * e + 16] = gu0[e];
  if (gbs) for (int e = tid; e < 1156; e += 256) gate[e] = gbs[e];
  c32* gbase = psi + (size_t)b * D4 + t * 16;
  if (c0) {
    if (tid < 48) cv[tid / 12][tid % 12] = c0[(size_t)b * 48 + tid];
    __syncthreads();
    for (int e = tid; e < 2304; e += 256) {
      int row = e >> 4, q = e & 15;
      int cc = 16 * t + q, n2 = cc / 12, n3 = cc - 12 * n2;
      buf[KP * row + q] =
          cmul(cmul(cv[0][row / 12], cv[1][row % 12]), cmul(cv[2][n2], cv[3][n3]));
    }
  } else {
    for (int e = tid; e < 1152; e += 256) {
      int row = e >> 3, q = e & 7;
      ((float4*)(buf + row * KP))[q] = ((const float4*)(gbase + (size_t)row * 144))[q];
    }
  }
  __syncthreads();
  c32 acc[16];
  // ---- U0 on n0: out row 12i+n1 reads rows 12j+n1; gate from pad col 16
  if (gu0) {
    if (tid < 144) {
      const int i = tid / 12, n1 = tid - 12 * (tid / 12);
#pragma unroll
      for (int n = 0; n < 16; ++n) acc[n] = CZERO;
#pragma unroll
      for (int j = 0; j < 12; ++j) {
        c32 g = buf[(i * 12 + j) * KP + 16];
        const float4* ip = (const float4*)(buf + (12 * j + n1) * KP);
        float4 w[8];
#pragma unroll
        for (int q = 0; q < 8; ++q) w[q] = ip[q];
#pragma unroll
        for (int n = 0; n < 16; ++n) acc[n] = cfma(g, get2(w, n), acc[n]);
      }
    }
    __syncthreads();
    if (tid < 144) {
      float4* op = (float4*)(buf + tid * KP);
#pragma unroll
      for (int q = 0; q < 8; ++q) op[q] = pack2(acc[2 * q], acc[2 * q + 1]);
    }
    __syncthreads();
  }
  // ---- BS(0,1): pattern rows (n0,n1); sector-sorted tasks, transposed gate walk
  if (gbs) {
    const int rb = (tid < 144) ? (int)d_perm[tid] : 0;
    if (tid < 144) {
      const RM m = rmeta(rb);
#pragma unroll
      for (int n = 0; n < 16; ++n) acc[n] = CZERO;
      int rho = m.r0, go = m.goff;
      for (int tk = 0; tk < m.sz; ++tk) {
        c32 g = gate[go];
        go += m.sz;
        const float4* ip = (const float4*)(buf + rho * KP);
        float4 w[8];
#pragma unroll
        for (int q = 0; q < 8; ++q) w[q] = ip[q];
#pragma unroll
        for (int n = 0; n < 16; ++n) acc[n] = cfma(g, get2(w, n), acc[n]);
        rho += m.dr;
      }
    }
    __syncthreads();
    if (tid < 144) {
      float4* op = (float4*)(buf + rb * KP);
#pragma unroll
      for (int q = 0; q < 8; ++q) op[q] = pack2(acc[2 * q], acc[2 * q + 1]);
    }
    __syncthreads();
  }
  for (int e = tid; e < 1152; e += 256) {
    int row = e >> 3, q = e & 7;
    ((float4*)(gbase + (size_t)row * 144))[q] = ((const float4*)(buf + row * KP))[q];
  }
}

// ---------------- expvals: <X_m> = sum 2*sqrt(n+1)*Re(conj(psi_n) psi_{n+1}) ----------------
__global__ __launch_bounds__(256) void expval_kernel(const c32* __restrict__ psi, float* __restrict__ out) {
  __shared__ float red[1024];
  __shared__ float sq2[12];
  const int tid = threadIdx.x, b = blockIdx.x;
  if (tid < 12) sq2[tid] = 2.f * sqrtf((float)(tid + 1));
  __syncthreads();
  const c32* base = psi + (size_t)b * D4;
  float a0 = 0.f, a1 = 0.f, a2 = 0.f, a3 = 0.f;
  for (int e = tid; e < D4; e += 256) {
    c32 p = base[e];
    int n3 = e % 12, t = e / 12;
    int n2 = t % 12; t /= 12;
    int n1 = t % 12, n0 = t / 12;
    if (n3 < 11) { c32 q = base[e + 1];    a3 = fmaf(sq2[n3], fmaf(p.x, q.x, p.y * q.y), a3); }
    if (n2 < 11) { c32 q = base[e + 12];   a2 = fmaf(sq2[n2], fmaf(p.x, q.x, p.y * q.y), a2); }
    if (n1 < 11) { c32 q = base[e + 144];  a1 = fmaf(sq2[n1], fmaf(p.x, q.x, p.y * q.y), a1); }
    if (n0 < 11) { c32 q = base[e + 1728]; a0 = fmaf(sq2[n0], fmaf(p.x, q.x, p.y * q.y), a0); }
  }
  red[tid * 4 + 0] = a0; red[tid * 4 + 1] = a1; red[tid * 4 + 2] = a2; red[tid * 4 + 3] = a3;
  __syncthreads();
  for (int s = 128; s > 0; s >>= 1) {
    if (tid < s) {
      red[tid * 4 + 0] += red[(tid + s) * 4 + 0];
      red[tid * 4 + 1] += red[(tid + s) * 4 + 1];
      red[tid * 4 + 2] += red[(tid + s) * 4 + 2];
      red[tid * 4 + 3] += red[(tid + s) * 4 + 3];
    }
    __syncthreads();
  }
  if (tid < 4) out[b * 4 + tid] = red[tid];
}

extern "C" void kernel_launch(void* const* d_in, const int* in_sizes, int n_in,
                              void* d_out, int out_size, void* d_ws, size_t ws_size,
                              hipStream_t stream) {
  const float* x      = (const float*)d_in[0];
  const float* theta1 = (const float*)d_in[1];
  const float* phi1   = (const float*)d_in[2];
  const float* vphi1  = (const float*)d_in[3];
  const float* r_     = (const float*)d_in[4];
  const float* phir   = (const float*)d_in[5];
  const float* theta2 = (const float*)d_in[6];
  const float* phi2   = (const float*)d_in[7];
  const float* vphi2  = (const float*)d_in[8];
  const float* a_     = (const float*)d_in[9];
  const float* phia   = (const float*)d_in[10];
  const float* kk     = (const float*)d_in[11];
  float* out = (float*)d_out;

  // workspace layout (bytes)
  const size_t PSI_OFF = 0;                              // 1024*20736*8
  const size_t C0_OFF  = 169869312;                      // 1024*4*12*8
  const size_t P1_OFF  = C0_OFF + 393216;
  const size_t P2_OFF  = P1_OFF + 9216;
  const size_t BS_OFF  = P2_OFF + 9216;                  // 24*1156*8
  const size_t NEED    = BS_OFF + 221952;
  if (ws_size < NEED) return;

  char* ws = (char*)d_ws;
  c32* psi = (c32*)(ws + PSI_OFF);
  c32* c0  = (c32*)(ws + C0_OFF);
  c32* P1  = (c32*)(ws + P1_OFF);
  c32* P2  = (c32*)(ws + P2_OFF);
  c32* BS  = (c32*)(ws + BS_OFF);

  prep_disp<<<dim3(4096), dim3(64), 0, stream>>>(x, c0);
  prep_bs<<<dim3(552), dim3(64), 0, stream>>>(theta1, phi1, theta2, phi2, BS);
  prep_p<<<dim3(16), dim3(64), 0, stream>>>(r_, phir, vphi1, a_, phia, vphi2, kk, P1, P2);

  for (int l = 0; l < 2; ++l) {
    c32* bsl = BS + (size_t)l * 12 * 1156;
    const c32* c0arg = (l == 0) ? c0 : (const c32*)nullptr;
    const c32* u0pre = (l == 0) ? (const c32*)nullptr : (const c32*)(P2 + (size_t)(l - 1) * 4 * 144);
    // interferometer 1: Clements order (0,1),(2,3),(1,2),(0,1),(2,3),(1,2)
    k01_kernel<<<dim3(9216), dim3(256), 0, stream>>>(psi, c0arg, u0pre, bsl + 0 * 1156);
    k123_kernel<<<dim3(12288), dim3(256), 0, stream>>>(psi, bsl + 1 * 1156, bsl + 2 * 1156,
                                                       nullptr, nullptr, nullptr);
    k01_kernel<<<dim3(9216), dim3(256), 0, stream>>>(psi, nullptr, nullptr, bsl + 3 * 1156);
    k123_kernel<<<dim3(12288), dim3(256), 0, stream>>>(psi, bsl + 4 * 1156, bsl + 5 * 1156,
                                                       P1 + (size_t)(l * 4 + 1) * 144,
                                                       P1 + (size_t)(l * 4 + 2) * 144,
                                                       P1 + (size_t)(l * 4 + 3) * 144);
    // interferometer 2 (P1 mode-0 composite rides along before its first BS(0,1))
    k01_kernel<<<dim3(9216), dim3(256), 0, stream>>>(psi, nullptr, P1 + (size_t)(l * 4 + 0) * 144, bsl + 6 * 1156);
    k123_kernel<<<dim3(12288), dim3(256), 0, stream>>>(psi, bsl + 7 * 1156, bsl + 8 * 1156,
                                                       nullptr, nullptr, nullptr);
    k01_kernel<<<dim3(9216), dim3(256), 0, stream>>>(psi, nullptr, nullptr, bsl + 9 * 1156);
    k123_kernel<<<dim3(12288), dim3(256), 0, stream>>>(psi, bsl + 10 * 1156, bsl + 11 * 1156,
                                                       P2 + (size_t)(l * 4 + 1) * 144,
                                                       P2 + (size_t)(l * 4 + 2) * 144,
                                                       P2 + (size_t)(l * 4 + 3) * 144);
  }
  // final pending mode-0 composite from layer 2
  k01_kernel<<<dim3(9216), dim3(256), 0, stream>>>(psi, nullptr, P2 + (size_t)(1 * 4 + 0) * 144, nullptr);
  expval_kernel<<<dim3(1024), dim3(256), 0, stream>>>(psi, out);
}

// Round 11
// 1966.093 us; speedup vs baseline: 1.1111x; 1.0473x over previous
//
#include <hip/hip_runtime.h>
#include <math.h>

#define D4 20736
#define ST 14    // k123 LDS row stride (c32), 112B; cols 12,13 = pad storage for gV1/gV2
#define SST 168  // 12*ST: spectator stride for bs23
#define KP 18    // k01 LDS row stride (c32), 144B; col 16 = pad storage for g0v

typedef float c32 __attribute__((ext_vector_type(2)));

__device__ __forceinline__ c32 C2(float x, float y) { c32 r; r.x = x; r.y = y; return r; }
#define CZERO C2(0.f, 0.f)

__device__ __forceinline__ c32 cmul(c32 a, c32 b) {
  return C2(a.x * b.x - a.y * b.y, a.x * b.y + a.y * b.x);
}
// scalar complex FMA (prep kernels — keeps gate generation independent of asm path)
__device__ __forceinline__ c32 cfma_s(c32 a, c32 b, c32 acc) {
  acc.x = fmaf(a.x, b.x, fmaf(-a.y, b.y, acc.x));
  acc.y = fmaf(a.x, b.y, fmaf(a.y, b.x, acc.y));
  return acc;
}
// packed complex FMA: acc += g*v in 2 x v_pk_fma_f32
//   t.lo = acc.x + g.x*v.x ; t.hi = acc.y + g.x*v.y        (op_sel_hi:[0,1,1])
//   d.lo = t.lo  - g.y*v.y ; d.hi = t.hi  + g.y*v.x        (op_sel:[1,1,0] op_sel_hi:[1,0,1] neg_lo:[1,0,0])
__device__ __forceinline__ c32 cfma(c32 g, c32 v, c32 acc) {
  c32 t, d;
  asm("v_pk_fma_f32 %0, %1, %2, %3 op_sel_hi:[0,1,1]"
      : "=v"(t) : "v"(g), "v"(v), "v"(acc));
  asm("v_pk_fma_f32 %0, %1, %2, %3 op_sel:[1,1,0] op_sel_hi:[1,0,1] neg_lo:[1,0,0]"
      : "=v"(d) : "v"(g), "v"(v), "v"(t));
  return d;
}
__device__ __forceinline__ c32 get2(const float4* w, int n) {
  float4 q = w[n >> 1];
  return (n & 1) ? C2(q.z, q.w) : C2(q.x, q.y);
}
__device__ __forceinline__ float4 pack2(c32 a, c32 b) {
  return make_float4(a.x, a.y, b.x, b.y);
}

// sector offsets: secoff[N] = sum_{n<N} sz(n)^2
__constant__ int d_secoff[24] = {0,1,5,14,30,55,91,140,204,285,385,506,650,
                                 771,871,952,1016,1065,1101,1126,1142,1151,1155,1156};

// rows sorted by descending sector size -> per-wave loop-trip maxima 12/9/4
__constant__ unsigned char d_perm[144] = {
  11,22,33,44,55,66,77,88,99,110,121,132,
  10,21,32,43,54,65,76,87,98,109,120,
  23,34,45,56,67,78,89,100,111,122,133,
  9,20,31,42,53,64,75,86,97,108,
  35,46,57,68,79,90,101,112,123,134,
  8,19,30,41,52,63,74,85,96,
  47,58,69,80,91,102,113,124,135,
  7,18,29,40,51,62,73,84,
  59,70,81,92,103,114,125,136,
  6,17,28,39,50,61,72,
  71,82,93,104,115,126,137,
  5,16,27,38,49,60,
  83,94,105,116,127,138,
  4,15,26,37,48,
  95,106,117,128,139,
  3,14,25,36,
  107,118,129,140,
  2,13,24,
  119,130,141,
  1,12,
  131,142,
  0,
  143
};

struct RM { int goff, sz, a0, da, r0, dr; };
// metadata for output pattern-row r=(i,j). Gates stored TRANSPOSED per sector:
// element (p=i-lo, walk-step t) at secoff + t*sz + p. goff walks += sz per step.
// Down-sectors iterate descending (prep_bs stores column-reversed).
__device__ __forceinline__ RM rmeta(int r) {
  const int i = r / 12, j = r - 12 * i, N = i + j;
  const bool up = (N <= 11);
  RM m;
  m.sz = (up ? N : 22 - N) + 1;
  const int lo = up ? 0 : (N - 11);
  m.goff = d_secoff[N] + (i - lo);
  m.a0 = up ? N : (143 + N);
  m.da = up ? 13 : -13;
  m.r0 = up ? N : (121 + N);
  m.dr = up ? 11 : -11;
  return m;
}

// ---------------- small matrix expm (LDS, 64-thread block) ----------------
__device__ void small_expm(c32* A, c32* S, c32* P, c32* T, float* red, int sz, int tid) {
  const int n2 = sz * sz;
  if (tid < sz) {
    float s = 0.f;
    for (int j = 0; j < sz; ++j) { c32 v = A[tid * sz + j]; s += sqrtf(fmaf(v.x, v.x, v.y * v.y)); }
    red[tid] = s;
  }
  __syncthreads();
  float nrm = 0.f;
  for (int i = 0; i < sz; ++i) nrm = fmaxf(nrm, red[i]);
  int sp = 0;
  while (nrm > 0.35f && sp < 24) { nrm *= 0.5f; ++sp; }
  const float scale = ldexpf(1.f, -sp);
  for (int e = tid; e < n2; e += 64) { A[e].x *= scale; A[e].y *= scale; }
  __syncthreads();
  for (int e = tid; e < n2; e += 64) {
    c32 a = A[e];
    P[e] = a;
    if ((e / sz) == (e % sz)) a.x += 1.f;
    S[e] = a;
  }
  __syncthreads();
  for (int k = 2; k <= 12; ++k) {
    const float inv = 1.f / (float)k;
    for (int e = tid; e < n2; e += 64) {
      int i = e / sz, j = e - i * sz;
      c32 acc = CZERO;
      for (int q = 0; q < sz; ++q) acc = cfma_s(P[i * sz + q], A[q * sz + j], acc);
      acc.x *= inv; acc.y *= inv;
      T[e] = acc;
    }
    __syncthreads();
    for (int e = tid; e < n2; e += 64) {
      c32 t = T[e];
      P[e] = t;
      S[e].x += t.x; S[e].y += t.y;
    }
    __syncthreads();
  }
  for (int q = 0; q < sp; ++q) {
    for (int e = tid; e < n2; e += 64) {
      int i = e / sz, j = e - i * sz;
      c32 acc = CZERO;
      for (int w = 0; w < sz; ++w) acc = cfma_s(S[i * sz + w], S[w * sz + j], acc);
      T[e] = acc;
    }
    __syncthreads();
    for (int e = tid; e < n2; e += 64) S[e] = T[e];
    __syncthreads();
  }
}

// ---------------- prep: per-batch displacement encoding (store col 0) ----------------
__global__ __launch_bounds__(64) void prep_disp(const float* __restrict__ x, c32* __restrict__ c0) {
  __shared__ c32 A[144], S[144], P[144], T[144];
  __shared__ float red[12];
  const int tid = threadIdx.x;
  const int b = blockIdx.x >> 2, m = blockIdx.x & 3;
  const float rr = x[b * 8 + m], ph = x[b * 8 + 4 + m];
  float sn, cs;
  sincosf(ph, &sn, &cs);
  const c32 alpha = C2(rr * cs, rr * sn);
  for (int e = tid; e < 144; e += 64) A[e] = CZERO;
  __syncthreads();
  if (tid < 11) {
    float sq = sqrtf((float)(tid + 1));
    A[(tid + 1) * 12 + tid] = C2(alpha.x * sq, alpha.y * sq);
    A[tid * 12 + tid + 1] = C2(-alpha.x * sq, alpha.y * sq);
  }
  __syncthreads();
  small_expm(A, S, P, T, red, 12, tid);
  if (tid < 12) c0[(size_t)blockIdx.x * 12 + tid] = S[tid * 12];
}

// ---------------- prep: beamsplitter sector blocks (transposed, direction-arranged) ----------------
__global__ __launch_bounds__(64) void prep_bs(const float* __restrict__ th1, const float* __restrict__ ph1,
                                              const float* __restrict__ th2, const float* __restrict__ ph2,
                                              c32* __restrict__ BS) {
  __shared__ c32 A[144], S[144], P[144], T[144];
  __shared__ float red[12];
  const int tid = threadIdx.x;
  const int g = blockIdx.x / 23, N = blockIdx.x % 23;
  const int l = g / 12, rem = g % 12, w = rem / 6, gi = rem % 6;
  const float th = (w ? th2 : th1)[l * 6 + gi];
  const float ph = (w ? ph2 : ph1)[l * 6 + gi];
  const int lo = (N > 11) ? (N - 11) : 0;
  const int sz = (N <= 11) ? (N + 1) : (23 - N);
  float sn, cs;
  sincosf(ph, &sn, &cs);
  for (int e = tid; e < sz * sz; e += 64) A[e] = CZERO;
  __syncthreads();
  if (tid + 1 < sz) {
    int t = tid + 1;
    float s1 = th * sqrtf((float)((lo + t) * (N - lo - t + 1)));
    A[(t - 1) * sz + t] = C2(cs * s1, sn * s1);
    A[t * sz + t - 1] = C2(-cs * s1, sn * s1);
  }
  __syncthreads();
  small_expm(A, S, P, T, red, sz, tid);
  // store TRANSPOSED: (p, walk-step q) -> dst[q*sz + p]; down-sectors column-reversed
  c32* dst = BS + (size_t)g * 1156 + d_secoff[N];
  const bool upSec = (N <= 11);
  for (int e = tid; e < sz * sz; e += 64) {
    int p = e / sz, q = e - p * sz;
    int qs = upSec ? q : (sz - 1 - q);
    dst[q * sz + p] = S[p * sz + qs];
  }
}

// ---------------- prep: per-mode composites P1 = S*R1, P2 = K*Disp*R2 ----------------
__global__ __launch_bounds__(64) void prep_p(const float* __restrict__ r_, const float* __restrict__ phir,
                                             const float* __restrict__ vphi1,
                                             const float* __restrict__ a_, const float* __restrict__ phia,
                                             const float* __restrict__ vphi2, const float* __restrict__ kk,
                                             c32* __restrict__ P1, c32* __restrict__ P2) {
  __shared__ c32 A[144], S[144], P[144], T[144];
  __shared__ float red[12];
  const int tid = threadIdx.x;
  const int which = blockIdx.x >> 3, lm = blockIdx.x & 7;
  for (int e = tid; e < 144; e += 64) A[e] = CZERO;
  __syncthreads();
  if (which == 0) {
    const float rv = r_[lm], pv = phir[lm];
    float sn, cs;
    sincosf(pv, &sn, &cs);
    const c32 z = C2(rv * cs, rv * sn);
    if (tid < 10) {
      float sq = 0.5f * sqrtf((float)((tid + 1) * (tid + 2)));
      A[tid * 12 + tid + 2] = C2(z.x * sq, -z.y * sq);
      A[(tid + 2) * 12 + tid] = C2(-z.x * sq, -z.y * sq);
    }
  } else {
    const float av = a_[lm], pv = phia[lm];
    float sn, cs;
    sincosf(pv, &sn, &cs);
    const c32 alpha = C2(av * cs, av * sn);
    if (tid < 11) {
      float sq = sqrtf((float)(tid + 1));
      A[(tid + 1) * 12 + tid] = C2(alpha.x * sq, alpha.y * sq);
      A[tid * 12 + tid + 1] = C2(-alpha.x * sq, alpha.y * sq);
    }
  }
  __syncthreads();
  small_expm(A, S, P, T, red, 12, tid);
  if (which == 0) {
    const float vp = vphi1[lm];
    for (int e = tid; e < 144; e += 64) {
      int j = e % 12;
      float sn, cs;
      sincosf(vp * (float)j, &sn, &cs);
      P1[(size_t)lm * 144 + e] = cmul(S[e], C2(cs, sn));
    }
  } else {
    const float vp = vphi2[lm], kv = kk[lm];
    for (int e = tid; e < 144; e += 64) {
      int i = e / 12, j = e % 12;
      float sn1, cs1, sn2, cs2;
      sincosf(vp * (float)j, &sn1, &cs1);
      float ang = kv * (float)i;
      ang *= (float)i;
      sincosf(ang, &sn2, &cs2);
      P2[(size_t)lm * 144 + e] = cmul(C2(cs2, sn2), cmul(S[e], C2(cs1, sn1)));
    }
  }
}

// ---------------- fused pass over modes {1,2,3}: BS(2,3) -> BS(1,2) -> U1 -> U2 -> U3 ----------------
// Slab (b,n0) of 1728 c32; in-place LDS [144][14]; pads hold gV1/gV2; gate buffer
// reused bs23 -> bs12 (reg-prefetched) -> gV3. U passes use (row-pair, col-half) tasks.
__global__ __launch_bounds__(256, 6) void k123_kernel(
    c32* __restrict__ psi,
    const c32* __restrict__ gbs23, const c32* __restrict__ gbs12,
    const c32* __restrict__ gu1, const c32* __restrict__ gu2, const c32* __restrict__ gu3) {
  __shared__ __align__(16) c32 buf[2016];
  __shared__ c32 gate[1168];
  const int tid = threadIdx.x;
  c32 pf[5];
#pragma unroll
  for (int k = 0; k < 5; ++k) {
    int e = tid + 256 * k;
    pf[k] = (e < 1156) ? gbs12[e] : CZERO;
  }
  c32 pf3 = (gu3 && tid < 144) ? gu3[tid] : CZERO;
  if (gu1) for (int e = tid; e < 144; e += 256) buf[ST * e + 12] = gu1[e];
  if (gu2) for (int e = tid; e < 144; e += 256) buf[ST * e + 13] = gu2[e];
  for (int e = tid; e < 1156; e += 256) gate[e] = gbs23[e];
  c32* slab = psi + (size_t)blockIdx.x * 1728;
  for (int v = tid; v < 864; v += 256) {
    float4 q = ((const float4*)slab)[v];
    *((float4*)buf + 7 * (v / 6) + (v % 6)) = q;
  }
  __syncthreads();
  const int rb = (tid < 144) ? (int)d_perm[tid] : 0;
  RM m;
  if (tid < 144) m = rmeta(rb);
  c32 acc[12];
  // ---- pass 1: BS(2,3): pattern (n2,n3) within each 168-stride n1-block
  if (tid < 144) {
#pragma unroll
    for (int n = 0; n < 12; ++n) acc[n] = CZERO;
    int a = m.a0, go = m.goff;
    for (int t = 0; t < m.sz; ++t) {
      c32 g = gate[go];
      go += m.sz;
#pragma unroll
      for (int n = 0; n < 12; ++n) acc[n] = cfma(g, buf[SST * n + a], acc[n]);
      a += m.da;
    }
  }
  __syncthreads();
  if (tid < 144) {
    const int wr = ST * (rb / 12) + (rb % 12);
#pragma unroll
    for (int n = 0; n < 12; ++n) buf[SST * n + wr] = acc[n];
  }
#pragma unroll
  for (int k = 0; k < 5; ++k) {
    int e = tid + 256 * k;
    if (e < 1156) gate[e] = pf[k];
  }
  __syncthreads();
  // ---- pass 2: BS(1,2): pattern rows (n1,n2), spectator n3 in-row (b128)
  if (tid < 144) {
#pragma unroll
    for (int n = 0; n < 12; ++n) acc[n] = CZERO;
    int rho = m.r0, go = m.goff;
    for (int t = 0; t < m.sz; ++t) {
      c32 g = gate[go];
      go += m.sz;
      const float4* ip = (const float4*)buf + 7 * rho;
      float4 w[6];
#pragma unroll
      for (int q = 0; q < 6; ++q) w[q] = ip[q];
#pragma unroll
      for (int n = 0; n < 12; ++n) acc[n] = cfma(g, get2(w, n), acc[n]);
      rho += m.dr;
    }
  }
  __syncthreads();
  if (tid < 144) {
    float4* op = (float4*)buf + 7 * rb;
#pragma unroll
    for (int q = 0; q < 6; ++q) op[q] = pack2(acc[2 * q], acc[2 * q + 1]);
  }
  if (gu3 && tid < 144) gate[tid] = pf3;  // gate buffer free now: stash gV3
  // ---- U1 on n1: task (pair p=k*12+n2, half h): outputs rows (2k)*12+n2, (2k+1)*12+n2
  if (gu1) {
    __syncthreads();
    if (tid < 144) {
      const int p = tid >> 1, h = tid & 1;
      const int k2 = p / 12, n2 = p - 12 * (p / 12);
      c32 a0[6], a1[6];
#pragma unroll
      for (int n = 0; n < 6; ++n) { a0[n] = CZERO; a1[n] = CZERO; }
#pragma unroll
      for (int j = 0; j < 12; ++j) {
        c32 g0 = buf[ST * ((2 * k2) * 12 + j) + 12];
        c32 g1 = buf[ST * ((2 * k2 + 1) * 12 + j) + 12];
        const float4* ip = (const float4*)buf + 7 * (12 * j + n2) + 3 * h;
        float4 w0 = ip[0], w1 = ip[1], w2 = ip[2];
        c32 v[6] = {C2(w0.x,w0.y), C2(w0.z,w0.w), C2(w1.x,w1.y),
                    C2(w1.z,w1.w), C2(w2.x,w2.y), C2(w2.z,w2.w)};
#pragma unroll
        for (int n = 0; n < 6; ++n) {
          a0[n] = cfma(g0, v[n], a0[n]);
          a1[n] = cfma(g1, v[n], a1[n]);
        }
      }
#pragma unroll
      for (int n = 0; n < 6; ++n) { acc[n] = a0[n]; acc[6 + n] = a1[n]; }
    }
    __syncthreads();
    if (tid < 144) {
      const int p = tid >> 1, h = tid & 1;
      const int k2 = p / 12, n2 = p - 12 * (p / 12);
      float4* opA = (float4*)buf + 7 * ((2 * k2) * 12 + n2) + 3 * h;
      float4* opB = (float4*)buf + 7 * ((2 * k2 + 1) * 12 + n2) + 3 * h;
      opA[0] = pack2(acc[0], acc[1]); opA[1] = pack2(acc[2], acc[3]); opA[2] = pack2(acc[4], acc[5]);
      opB[0] = pack2(acc[6], acc[7]); opB[1] = pack2(acc[8], acc[9]); opB[2] = pack2(acc[10], acc[11]);
    }
  }
  // ---- U2 on n2: task (pair p=n1*6+k, half h): outputs rows n1*12+2k, n1*12+2k+1
  if (gu2) {
    __syncthreads();
    if (tid < 144) {
      const int p = tid >> 1, h = tid & 1;
      const int n1 = p / 6, k2 = p - 6 * (p / 6);
      c32 a0[6], a1[6];
#pragma unroll
      for (int n = 0; n < 6; ++n) { a0[n] = CZERO; a1[n] = CZERO; }
#pragma unroll
      for (int j = 0; j < 12; ++j) {
        c32 g0 = buf[ST * ((2 * k2) * 12 + j) + 13];
        c32 g1 = buf[ST * ((2 * k2 + 1) * 12 + j) + 13];
        const float4* ip = (const float4*)buf + 7 * (12 * n1 + j) + 3 * h;
        float4 w0 = ip[0], w1 = ip[1], w2 = ip[2];
        c32 v[6] = {C2(w0.x,w0.y), C2(w0.z,w0.w), C2(w1.x,w1.y),
                    C2(w1.z,w1.w), C2(w2.x,w2.y), C2(w2.z,w2.w)};
#pragma unroll
        for (int n = 0; n < 6; ++n) {
          a0[n] = cfma(g0, v[n], a0[n]);
          a1[n] = cfma(g1, v[n], a1[n]);
        }
      }
#pragma unroll
      for (int n = 0; n < 6; ++n) { acc[n] = a0[n]; acc[6 + n] = a1[n]; }
    }
    __syncthreads();
    if (tid < 144) {
      const int p = tid >> 1, h = tid & 1;
      const int n1 = p / 6, k2 = p - 6 * (p / 6);
      float4* opA = (float4*)buf + 7 * (12 * n1 + 2 * k2) + 3 * h;
      float4* opB = (float4*)buf + 7 * (12 * n1 + 2 * k2 + 1) + 3 * h;
      opA[0] = pack2(acc[0], acc[1]); opA[1] = pack2(acc[2], acc[3]); opA[2] = pack2(acc[4], acc[5]);
      opB[0] = pack2(acc[6], acc[7]); opB[1] = pack2(acc[8], acc[9]); opB[2] = pack2(acc[10], acc[11]);
    }
  }
  // ---- U3 on n3: in-row; gate stashed in gate[0..143]
  if (gu3) {
    __syncthreads();
    if (tid < 144) {
      const float4* ip = (const float4*)buf + 7 * tid;
      float4 wv[6];
#pragma unroll
      for (int q = 0; q < 6; ++q) wv[q] = ip[q];
      float4* op = (float4*)buf + 7 * tid;
#pragma unroll
      for (int cpair = 0; cpair < 6; ++cpair) {
        c32 s0 = CZERO, s1 = CZERO;
#pragma unroll
        for (int j = 0; j < 12; ++j) {
          c32 v = get2(wv, j);
          s0 = cfma(gate[(2 * cpair) * 12 + j], v, s0);
          s1 = cfma(gate[(2 * cpair + 1) * 12 + j], v, s1);
        }
        op[cpair] = pack2(s0, s1);
      }
    }
  }
  __syncthreads();
  for (int v = tid; v < 864; v += 256) {
    ((float4*)slab)[v] = *((const float4*)buf + 7 * (v / 6) + (v % 6));
  }
}

// ---------------- fused pass over modes {0,1}: [init] -> U0 -> BS(0,1) ----------------
// Tile = 144 (n0,n1)-rows x 16 flat cols; in-place LDS [144][18]; pad col 16 = g0v.
__global__ __launch_bounds__(256, 5) void k01_kernel(
    c32* __restrict__ psi, const c32* __restrict__ c0,
    const c32* __restrict__ gu0, const c32* __restrict__ gbs) {
  __shared__ __align__(16) c32 buf[2592];
  __shared__ c32 gate[1168];
  __shared__ c32 cv[4][12];
  const int tid = threadIdx.x;
  const int b = blockIdx.x / 9, t = blockIdx.x % 9;
  if (gu0) for (int e = tid; e < 144; e += 256) buf[KP * e + 16] = gu0[e];
  if (gbs) for (int e = tid; e < 1156; e += 256) gate[e] = gbs[e];
  c32* gbase = psi + (size_t)b * D4 + t * 16;
  if (c0) {
    if (tid < 48) cv[tid / 12][tid % 12] = c0[(size_t)b * 48 + tid];
    __syncthreads();
    for (int e = tid; e < 2304; e += 256) {
      int row = e >> 4, q = e & 15;
      int cc = 16 * t + q, n2 = cc / 12, n3 = cc - 12 * n2;
      buf[KP * row + q] =
          cmul(cmul(cv[0][row / 12], cv[1][row % 12]), cmul(cv[2][n2], cv[3][n3]));
    }
  } else {
    for (int e = tid; e < 1152; e += 256) {
      int row = e >> 3, q = e & 7;
      ((float4*)(buf + row * KP))[q] = ((const float4*)(gbase + (size_t)row * 144))[q];
    }
  }
  __syncthreads();
  c32 acc[16];
  // ---- U0 on n0: task (pair p=k*12+n1, half h): outputs rows (2k)*12+n1, (2k+1)*12+n1
  if (gu0) {
    if (tid < 144) {
      const int p = tid >> 1, h = tid & 1;
      const int k2 = p / 12, n1 = p - 12 * (p / 12);
      c32 a0[8], a1[8];
#pragma unroll
      for (int n = 0; n < 8; ++n) { a0[n] = CZERO; a1[n] = CZERO; }
#pragma unroll
      for (int j = 0; j < 12; ++j) {
        c32 g0 = buf[((2 * k2) * 12 + j) * KP + 16];
        c32 g1 = buf[((2 * k2 + 1) * 12 + j) * KP + 16];
        const float4* ip = (const float4*)(buf + (12 * j + n1) * KP) + 4 * h;
        float4 w[4];
#pragma unroll
        for (int q = 0; q < 4; ++q) w[q] = ip[q];
#pragma unroll
        for (int n = 0; n < 8; ++n) {
          c32 v = get2(w, n);
          a0[n] = cfma(g0, v, a0[n]);
          a1[n] = cfma(g1, v, a1[n]);
        }
      }
#pragma unroll
      for (int n = 0; n < 8; ++n) { acc[n] = a0[n]; acc[8 + n] = a1[n]; }
    }
    __syncthreads();
    if (tid < 144) {
      const int p = tid >> 1, h = tid & 1;
      const int k2 = p / 12, n1 = p - 12 * (p / 12);
      float4* opA = (float4*)(buf + ((2 * k2) * 12 + n1) * KP) + 4 * h;
      float4* opB = (float4*)(buf + ((2 * k2 + 1) * 12 + n1) * KP) + 4 * h;
#pragma unroll
      for (int q = 0; q < 4; ++q) {
        opA[q] = pack2(acc[2 * q], acc[2 * q + 1]);
        opB[q] = pack2(acc[8 + 2 * q], acc[8 + 2 * q + 1]);
      }
    }
    __syncthreads();
  }
  // ---- BS(0,1): pattern rows (n0,n1); sector-sorted tasks, transposed gate walk
  if (gbs) {
    const int rb = (tid < 144) ? (int)d_perm[tid] : 0;
    if (tid < 144) {
      const RM m = rmeta(rb);
#pragma unroll
      for (int n = 0; n < 16; ++n) acc[n] = CZERO;
      int rho = m.r0, go = m.goff;
      for (int tk = 0; tk < m.sz; ++tk) {
        c32 g = gate[go];
        go += m.sz;
        const float4* ip = (const float4*)(buf + rho * KP);
        float4 w[8];
#pragma unroll
        for (int q = 0; q < 8; ++q) w[q] = ip[q];
#pragma unroll
        for (int n = 0; n < 16; ++n) acc[n] = cfma(g, get2(w, n), acc[n]);
        rho += m.dr;
      }
    }
    __syncthreads();
    if (tid < 144) {
      float4* op = (float4*)(buf + rb * KP);
#pragma unroll
      for (int q = 0; q < 8; ++q) op[q] = pack2(acc[2 * q], acc[2 * q + 1]);
    }
    __syncthreads();
  }
  for (int e = tid; e < 1152; e += 256) {
    int row = e >> 3, q = e & 7;
    ((float4*)(gbase + (size_t)row * 144))[q] = ((const float4*)(buf + row * KP))[q];
  }
}

// ---------------- expvals: <X_m> = sum 2*sqrt(n+1)*Re(conj(psi_n) psi_{n+1}) ----------------
__global__ __launch_bounds__(256) void expval_kernel(const c32* __restrict__ psi, float* __restrict__ out) {
  __shared__ float red[1024];
  __shared__ float sq2[12];
  const int tid = threadIdx.x, b = blockIdx.x;
  if (tid < 12) sq2[tid] = 2.f * sqrtf((float)(tid + 1));
  __syncthreads();
  const c32* base = psi + (size_t)b * D4;
  float a0 = 0.f, a1 = 0.f, a2 = 0.f, a3 = 0.f;
  for (int e = tid; e < D4; e += 256) {
    c32 p = base[e];
    int n3 = e % 12, t = e / 12;
    int n2 = t % 12; t /= 12;
    int n1 = t % 12, n0 = t / 12;
    if (n3 < 11) { c32 q = base[e + 1];    a3 = fmaf(sq2[n3], fmaf(p.x, q.x, p.y * q.y), a3); }
    if (n2 < 11) { c32 q = base[e + 12];   a2 = fmaf(sq2[n2], fmaf(p.x, q.x, p.y * q.y), a2); }
    if (n1 < 11) { c32 q = base[e + 144];  a1 = fmaf(sq2[n1], fmaf(p.x, q.x, p.y * q.y), a1); }
    if (n0 < 11) { c32 q = base[e + 1728]; a0 = fmaf(sq2[n0], fmaf(p.x, q.x, p.y * q.y), a0); }
  }
  red[tid * 4 + 0] = a0; red[tid * 4 + 1] = a1; red[tid * 4 + 2] = a2; red[tid * 4 + 3] = a3;
  __syncthreads();
  for (int s = 128; s > 0; s >>= 1) {
    if (tid < s) {
      red[tid * 4 + 0] += red[(tid + s) * 4 + 0];
      red[tid * 4 + 1] += red[(tid + s) * 4 + 1];
      red[tid * 4 + 2] += red[(tid + s) * 4 + 2];
      red[tid * 4 + 3] += red[(tid + s) * 4 + 3];
    }
    __syncthreads();
  }
  if (tid < 4) out[b * 4 + tid] = red[tid];
}

extern "C" void kernel_launch(void* const* d_in, const int* in_sizes, int n_in,
                              void* d_out, int out_size, void* d_ws, size_t ws_size,
                              hipStream_t stream) {
  const float* x      = (const float*)d_in[0];
  const float* theta1 = (const float*)d_in[1];
  const float* phi1   = (const float*)d_in[2];
  const float* vphi1  = (const float*)d_in[3];
  const float* r_     = (const float*)d_in[4];
  const float* phir   = (const float*)d_in[5];
  const float* theta2 = (const float*)d_in[6];
  const float* phi2   = (const float*)d_in[7];
  const float* vphi2  = (const float*)d_in[8];
  const float* a_     = (const float*)d_in[9];
  const float* phia   = (const float*)d_in[10];
  const float* kk     = (const float*)d_in[11];
  float* out = (float*)d_out;

  // workspace layout (bytes)
  const size_t PSI_OFF = 0;                              // 1024*20736*8
  const size_t C0_OFF  = 169869312;                      // 1024*4*12*8
  const size_t P1_OFF  = C0_OFF + 393216;
  const size_t P2_OFF  = P1_OFF + 9216;
  const size_t BS_OFF  = P2_OFF + 9216;                  // 24*1156*8
  const size_t NEED    = BS_OFF + 221952;
  if (ws_size < NEED) return;

  char* ws = (char*)d_ws;
  c32* psi = (c32*)(ws + PSI_OFF);
  c32* c0  = (c32*)(ws + C0_OFF);
  c32* P1  = (c32*)(ws + P1_OFF);
  c32* P2  = (c32*)(ws + P2_OFF);
  c32* BS  = (c32*)(ws + BS_OFF);

  prep_disp<<<dim3(4096), dim3(64), 0, stream>>>(x, c0);
  prep_bs<<<dim3(552), dim3(64), 0, stream>>>(theta1, phi1, theta2, phi2, BS);
  prep_p<<<dim3(16), dim3(64), 0, stream>>>(r_, phir, vphi1, a_, phia, vphi2, kk, P1, P2);

  for (int l = 0; l < 2; ++l) {
    c32* bsl = BS + (size_t)l * 12 * 1156;
    const c32* c0arg = (l == 0) ? c0 : (const c32*)nullptr;
    const c32* u0pre = (l == 0) ? (const c32*)nullptr : (const c32*)(P2 + (size_t)(l - 1) * 4 * 144);
    // interferometer 1: Clements order (0,1),(2,3),(1,2),(0,1),(2,3),(1,2)
    k01_kernel<<<dim3(9216), dim3(256), 0, stream>>>(psi, c0arg, u0pre, bsl + 0 * 1156);
    k123_kernel<<<dim3(12288), dim3(256), 0, stream>>>(psi, bsl + 1 * 1156, bsl + 2 * 1156,
                                                       nullptr, nullptr, nullptr);
    k01_kernel<<<dim3(9216), dim3(256), 0, stream>>>(psi, nullptr, nullptr, bsl + 3 * 1156);
    k123_kernel<<<dim3(12288), dim3(256), 0, stream>>>(psi, bsl + 4 * 1156, bsl + 5 * 1156,
                                                       P1 + (size_t)(l * 4 + 1) * 144,
                                                       P1 + (size_t)(l * 4 + 2) * 144,
                                                       P1 + (size_t)(l * 4 + 3) * 144);
    // interferometer 2 (P1 mode-0 composite rides along before its first BS(0,1))
    k01_kernel<<<dim3(9216), dim3(256), 0, stream>>>(psi, nullptr, P1 + (size_t)(l * 4 + 0) * 144, bsl + 6 * 1156);
    k123_kernel<<<dim3(12288), dim3(256), 0, stream>>>(psi, bsl + 7 * 1156, bsl + 8 * 1156,
                                                       nullptr, nullptr, nullptr);
    k01_kernel<<<dim3(9216), dim3(256), 0, stream>>>(psi, nullptr, nullptr, bsl + 9 * 1156);
    k123_kernel<<<dim3(12288), dim3(256), 0, stream>>>(psi, bsl + 10 * 1156, bsl + 11 * 1156,
                                                       P2 + (size_t)(l * 4 + 1) * 144,
                                                       P2 + (size_t)(l * 4 + 2) * 144,
                                                       P2 + (size_t)(l * 4 + 3) * 144);
  }
  // final pending mode-0 composite from layer 2
  k01_kernel<<<dim3(9216), dim3(256), 0, stream>>>(psi, nullptr, P2 + (size_t)(1 * 4 + 0) * 144, nullptr);
  expval_kernel<<<dim3(1024), dim3(256), 0, stream>>>(psi, out);
}

// Round 12
// 1888.362 us; speedup vs baseline: 1.1568x; 1.0412x over previous
//
#include <hip/hip_runtime.h>
#include <math.h>

#define D4 20736
#define ST 14    // k123 LDS row stride (c32), 112B; cols 12,13 = transposed gV1/gV2
#define SST 168  // 12*ST: spectator stride for bs23
#define KP 18    // k01 LDS row stride (c32), 144B; col 16 = transposed g0v

typedef float c32 __attribute__((ext_vector_type(2)));

__device__ __forceinline__ c32 C2(float x, float y) { c32 r; r.x = x; r.y = y; return r; }
#define CZERO C2(0.f, 0.f)

__device__ __forceinline__ c32 cmul(c32 a, c32 b) {
  return C2(a.x * b.x - a.y * b.y, a.x * b.y + a.y * b.x);
}
// scalar complex FMA (prep kernels)
__device__ __forceinline__ c32 cfma_s(c32 a, c32 b, c32 acc) {
  acc.x = fmaf(a.x, b.x, fmaf(-a.y, b.y, acc.x));
  acc.y = fmaf(a.x, b.y, fmaf(a.y, b.x, acc.y));
  return acc;
}
// packed complex FMA: acc += g*v in 2 x v_pk_fma_f32
__device__ __forceinline__ c32 cfma(c32 g, c32 v, c32 acc) {
  c32 t, d;
  asm("v_pk_fma_f32 %0, %1, %2, %3 op_sel_hi:[0,1,1]"
      : "=v"(t) : "v"(g), "v"(v), "v"(acc));
  asm("v_pk_fma_f32 %0, %1, %2, %3 op_sel:[1,1,0] op_sel_hi:[1,0,1] neg_lo:[1,0,0]"
      : "=v"(d) : "v"(g), "v"(v), "v"(t));
  return d;
}
__device__ __forceinline__ c32 get2(const float4* w, int n) {
  float4 q = w[n >> 1];
  return (n & 1) ? C2(q.z, q.w) : C2(q.x, q.y);
}
__device__ __forceinline__ float4 pack2(c32 a, c32 b) {
  return make_float4(a.x, a.y, b.x, b.y);
}

// sector offsets: secoff[N] = sum_{n<N} sz(n)^2
__constant__ int d_secoff[24] = {0,1,5,14,30,55,91,140,204,285,385,506,650,
                                 771,871,952,1016,1065,1101,1126,1142,1151,1155,1156};

// row-PAIR tasks sorted by descending sector size; code = N*8 + k
// (pair k covers sector rows 2k, 2k+1). Wave trip maxima: 12 / 9 / 5.
__constant__ unsigned char d_pp[78] = {
  88,89,90,91,92,93,        // N=11 sz12
  80,81,82,83,84,85,        // N=10 sz11
  96,97,98,99,100,101,      // N=12 sz11
  72,73,74,75,76,           // N=9  sz10
  104,105,106,107,108,      // N=13 sz10
  64,65,66,67,68,           // N=8  sz9
  112,113,114,115,116,      // N=14 sz9
  56,57,58,59,              // N=7  sz8
  120,121,122,123,          // N=15 sz8
  48,49,50,51,              // N=6  sz7
  128,129,130,131,          // N=16 sz7
  40,41,42,                 // N=5  sz6
  136,137,138,              // N=17 sz6
  32,33,34,                 // N=4  sz5
  144,145,146,              // N=18 sz5
  24,25,                    // N=3  sz4
  152,153,                  // N=19 sz4
  16,17,                    // N=2  sz3
  160,161,                  // N=20 sz3
  8,                        // N=1  sz2
  168,                      // N=21 sz2
  0,                        // N=0  sz1
  176                       // N=22 sz1
};

struct PM { int sz, goff, a0, da, r0, dr, w1, w2; bool v1; };
// pair metadata. Gates transposed per sector: (p, step t) at secoff + t*sz + p;
// pair reads gate[goff], gate[goff+1] (consecutive), goff += sz per step.
// a-walk (pass bs23, ST-flat units) and rho-walk (row units) are row-independent.
// Down-sectors iterate descending (prep_bs stores column-reversed).
__device__ __forceinline__ PM pmeta(int pr) {
  const int code = d_pp[pr];
  const int N = code >> 3, k = code & 7;
  const bool up = (N <= 11);
  PM m;
  m.sz = (up ? N : 22 - N) + 1;
  const int lo = up ? 0 : (N - 11);
  const int i0 = lo + 2 * k;
  m.v1 = (2 * k + 1 < m.sz);
  m.goff = d_secoff[N] + 2 * k;
  m.a0 = up ? N : (143 + N);
  m.da = up ? 13 : -13;
  m.r0 = up ? N : (121 + N);
  m.dr = up ? 11 : -11;
  m.w1 = 13 * i0 + N;   // pass1 write: ST*i0 + (N-i0); second row +13
  m.w2 = 11 * i0 + N;   // row-pass write row: 12*i0 + (N-i0); second row +11
  return m;
}

// ---------------- small matrix expm (LDS, 64-thread block) ----------------
__device__ void small_expm(c32* A, c32* S, c32* P, c32* T, float* red, int sz, int tid) {
  const int n2 = sz * sz;
  if (tid < sz) {
    float s = 0.f;
    for (int j = 0; j < sz; ++j) { c32 v = A[tid * sz + j]; s += sqrtf(fmaf(v.x, v.x, v.y * v.y)); }
    red[tid] = s;
  }
  __syncthreads();
  float nrm = 0.f;
  for (int i = 0; i < sz; ++i) nrm = fmaxf(nrm, red[i]);
  int sp = 0;
  while (nrm > 0.35f && sp < 24) { nrm *= 0.5f; ++sp; }
  const float scale = ldexpf(1.f, -sp);
  for (int e = tid; e < n2; e += 64) { A[e].x *= scale; A[e].y *= scale; }
  __syncthreads();
  for (int e = tid; e < n2; e += 64) {
    c32 a = A[e];
    P[e] = a;
    if ((e / sz) == (e % sz)) a.x += 1.f;
    S[e] = a;
  }
  __syncthreads();
  for (int k = 2; k <= 12; ++k) {
    const float inv = 1.f / (float)k;
    for (int e = tid; e < n2; e += 64) {
      int i = e / sz, j = e - i * sz;
      c32 acc = CZERO;
      for (int q = 0; q < sz; ++q) acc = cfma_s(P[i * sz + q], A[q * sz + j], acc);
      acc.x *= inv; acc.y *= inv;
      T[e] = acc;
    }
    __syncthreads();
    for (int e = tid; e < n2; e += 64) {
      c32 t = T[e];
      P[e] = t;
      S[e].x += t.x; S[e].y += t.y;
    }
    __syncthreads();
  }
  for (int q = 0; q < sp; ++q) {
    for (int e = tid; e < n2; e += 64) {
      int i = e / sz, j = e - i * sz;
      c32 acc = CZERO;
      for (int w = 0; w < sz; ++w) acc = cfma_s(S[i * sz + w], S[w * sz + j], acc);
      T[e] = acc;
    }
    __syncthreads();
    for (int e = tid; e < n2; e += 64) S[e] = T[e];
    __syncthreads();
  }
}

// ---------------- prep: per-batch displacement encoding (store col 0) ----------------
__global__ __launch_bounds__(64) void prep_disp(const float* __restrict__ x, c32* __restrict__ c0) {
  __shared__ c32 A[144], S[144], P[144], T[144];
  __shared__ float red[12];
  const int tid = threadIdx.x;
  const int b = blockIdx.x >> 2, m = blockIdx.x & 3;
  const float rr = x[b * 8 + m], ph = x[b * 8 + 4 + m];
  float sn, cs;
  sincosf(ph, &sn, &cs);
  const c32 alpha = C2(rr * cs, rr * sn);
  for (int e = tid; e < 144; e += 64) A[e] = CZERO;
  __syncthreads();
  if (tid < 11) {
    float sq = sqrtf((float)(tid + 1));
    A[(tid + 1) * 12 + tid] = C2(alpha.x * sq, alpha.y * sq);
    A[tid * 12 + tid + 1] = C2(-alpha.x * sq, alpha.y * sq);
  }
  __syncthreads();
  small_expm(A, S, P, T, red, 12, tid);
  if (tid < 12) c0[(size_t)blockIdx.x * 12 + tid] = S[tid * 12];
}

// ---------------- prep: beamsplitter sector blocks (transposed, direction-arranged) ----------------
__global__ __launch_bounds__(64) void prep_bs(const float* __restrict__ th1, const float* __restrict__ ph1,
                                              const float* __restrict__ th2, const float* __restrict__ ph2,
                                              c32* __restrict__ BS) {
  __shared__ c32 A[144], S[144], P[144], T[144];
  __shared__ float red[12];
  const int tid = threadIdx.x;
  const int g = blockIdx.x / 23, N = blockIdx.x % 23;
  const int l = g / 12, rem = g % 12, w = rem / 6, gi = rem % 6;
  const float th = (w ? th2 : th1)[l * 6 + gi];
  const float ph = (w ? ph2 : ph1)[l * 6 + gi];
  const int lo = (N > 11) ? (N - 11) : 0;
  const int sz = (N <= 11) ? (N + 1) : (23 - N);
  float sn, cs;
  sincosf(ph, &sn, &cs);
  for (int e = tid; e < sz * sz; e += 64) A[e] = CZERO;
  __syncthreads();
  if (tid + 1 < sz) {
    int t = tid + 1;
    float s1 = th * sqrtf((float)((lo + t) * (N - lo - t + 1)));
    A[(t - 1) * sz + t] = C2(cs * s1, sn * s1);
    A[t * sz + t - 1] = C2(-cs * s1, sn * s1);
  }
  __syncthreads();
  small_expm(A, S, P, T, red, sz, tid);
  // store TRANSPOSED: (p, walk-step q) -> dst[q*sz + p]; down-sectors column-reversed
  c32* dst = BS + (size_t)g * 1156 + d_secoff[N];
  const bool upSec = (N <= 11);
  for (int e = tid; e < sz * sz; e += 64) {
    int p = e / sz, q = e - p * sz;
    int qs = upSec ? q : (sz - 1 - q);
    dst[q * sz + p] = S[p * sz + qs];
  }
}

// ---------------- prep: per-mode composites P1 = S*R1, P2 = K*Disp*R2 ----------------
__global__ __launch_bounds__(64) void prep_p(const float* __restrict__ r_, const float* __restrict__ phir,
                                             const float* __restrict__ vphi1,
                                             const float* __restrict__ a_, const float* __restrict__ phia,
                                             const float* __restrict__ vphi2, const float* __restrict__ kk,
                                             c32* __restrict__ P1, c32* __restrict__ P2) {
  __shared__ c32 A[144], S[144], P[144], T[144];
  __shared__ float red[12];
  const int tid = threadIdx.x;
  const int which = blockIdx.x >> 3, lm = blockIdx.x & 7;
  for (int e = tid; e < 144; e += 64) A[e] = CZERO;
  __syncthreads();
  if (which == 0) {
    const float rv = r_[lm], pv = phir[lm];
    float sn, cs;
    sincosf(pv, &sn, &cs);
    const c32 z = C2(rv * cs, rv * sn);
    if (tid < 10) {
      float sq = 0.5f * sqrtf((float)((tid + 1) * (tid + 2)));
      A[tid * 12 + tid + 2] = C2(z.x * sq, -z.y * sq);
      A[(tid + 2) * 12 + tid] = C2(-z.x * sq, -z.y * sq);
    }
  } else {
    const float av = a_[lm], pv = phia[lm];
    float sn, cs;
    sincosf(pv, &sn, &cs);
    const c32 alpha = C2(av * cs, av * sn);
    if (tid < 11) {
      float sq = sqrtf((float)(tid + 1));
      A[(tid + 1) * 12 + tid] = C2(alpha.x * sq, alpha.y * sq);
      A[tid * 12 + tid + 1] = C2(-alpha.x * sq, alpha.y * sq);
    }
  }
  __syncthreads();
  small_expm(A, S, P, T, red, 12, tid);
  if (which == 0) {
    const float vp = vphi1[lm];
    for (int e = tid; e < 144; e += 64) {
      int j = e % 12;
      float sn, cs;
      sincosf(vp * (float)j, &sn, &cs);
      P1[(size_t)lm * 144 + e] = cmul(S[e], C2(cs, sn));
    }
  } else {
    const float vp = vphi2[lm], kv = kk[lm];
    for (int e = tid; e < 144; e += 64) {
      int i = e / 12, j = e % 12;
      float sn1, cs1, sn2, cs2;
      sincosf(vp * (float)j, &sn1, &cs1);
      float ang = kv * (float)i;
      ang *= (float)i;
      sincosf(ang, &sn2, &cs2);
      P2[(size_t)lm * 144 + e] = cmul(C2(cs2, sn2), cmul(S[e], C2(cs1, sn1)));
    }
  }
}

// ---------------- fused pass over modes {1,2,3}: BS(2,3) -> BS(1,2) -> U1 -> U2 -> U3 ----------------
// Slab (b,n0) of 1728 c32; in-place LDS [144][14]; pads hold TRANSPOSED gV1/gV2;
// gate buffer reused bs23 -> bs12 (reg-prefetched) -> gV3.
// BS passes: 156 (row-pair, spectator-half) tasks — each state read feeds 2 rows.
__global__ __launch_bounds__(256, 6) void k123_kernel(
    c32* __restrict__ psi,
    const c32* __restrict__ gbs23, const c32* __restrict__ gbs12,
    const c32* __restrict__ gu1, const c32* __restrict__ gu2, const c32* __restrict__ gu3) {
  __shared__ __align__(16) c32 buf[2016];
  __shared__ c32 gate[1168];
  const int tid = threadIdx.x;
  c32 pf[5];
#pragma unroll
  for (int k = 0; k < 5; ++k) {
    int e = tid + 256 * k;
    pf[k] = (e < 1156) ? gbs12[e] : CZERO;
  }
  c32 pf3 = (gu3 && tid < 144) ? gu3[tid] : CZERO;
  // gV1/gV2 transposed into pad cols: element (i,j) at row j*12+i
  if (gu1) for (int e = tid; e < 144; e += 256) buf[ST * ((e % 12) * 12 + e / 12) + 12] = gu1[e];
  if (gu2) for (int e = tid; e < 144; e += 256) buf[ST * ((e % 12) * 12 + e / 12) + 13] = gu2[e];
  for (int e = tid; e < 1156; e += 256) gate[e] = gbs23[e];
  c32* slab = psi + (size_t)blockIdx.x * 1728;
  for (int v = tid; v < 864; v += 256) {
    float4 q = ((const float4*)slab)[v];
    *((float4*)buf + 7 * (v / 6) + (v % 6)) = q;
  }
  __syncthreads();
  const int pr = tid >> 1, h = tid & 1;
  PM m;
  if (tid < 156) m = pmeta(pr);
  c32 acc0[6], acc1[6];
  // ---- pass 1: BS(2,3): pattern (n2,n3) within each 168-stride n1-block
  if (tid < 156) {
#pragma unroll
    for (int n = 0; n < 6; ++n) { acc0[n] = CZERO; acc1[n] = CZERO; }
    int a = m.a0 + 1008 * h, go = m.goff;
    for (int t = 0; t < m.sz; ++t) {
      c32 g0 = gate[go];
      c32 g1 = gate[go + 1];
      if (!m.v1) g1 = CZERO;
      go += m.sz;
#pragma unroll
      for (int n = 0; n < 6; ++n) {
        c32 v = buf[SST * n + a];
        acc0[n] = cfma(g0, v, acc0[n]);
        acc1[n] = cfma(g1, v, acc1[n]);
      }
      a += m.da;
    }
  }
  __syncthreads();
  if (tid < 156) {
    const int w0 = m.w1 + 1008 * h;
#pragma unroll
    for (int n = 0; n < 6; ++n) buf[SST * n + w0] = acc0[n];
    if (m.v1) {
#pragma unroll
      for (int n = 0; n < 6; ++n) buf[SST * n + w0 + 13] = acc1[n];
    }
  }
#pragma unroll
  for (int k = 0; k < 5; ++k) {
    int e = tid + 256 * k;
    if (e < 1156) gate[e] = pf[k];
  }
  __syncthreads();
  // ---- pass 2: BS(1,2): pattern rows (n1,n2), spectator n3 in-row (b128 halves)
  if (tid < 156) {
#pragma unroll
    for (int n = 0; n < 6; ++n) { acc0[n] = CZERO; acc1[n] = CZERO; }
    int rho = m.r0, go = m.goff;
    for (int t = 0; t < m.sz; ++t) {
      c32 g0 = gate[go];
      c32 g1 = gate[go + 1];
      if (!m.v1) g1 = CZERO;
      go += m.sz;
      const float4* ip = (const float4*)buf + 7 * rho + 3 * h;
      float4 w0 = ip[0], w1 = ip[1], w2 = ip[2];
      c32 v[6] = {C2(w0.x,w0.y), C2(w0.z,w0.w), C2(w1.x,w1.y),
                  C2(w1.z,w1.w), C2(w2.x,w2.y), C2(w2.z,w2.w)};
#pragma unroll
      for (int n = 0; n < 6; ++n) {
        acc0[n] = cfma(g0, v[n], acc0[n]);
        acc1[n] = cfma(g1, v[n], acc1[n]);
      }
      rho += m.dr;
    }
  }
  __syncthreads();
  if (tid < 156) {
    float4* opA = (float4*)buf + 7 * m.w2 + 3 * h;
    opA[0] = pack2(acc0[0], acc0[1]);
    opA[1] = pack2(acc0[2], acc0[3]);
    opA[2] = pack2(acc0[4], acc0[5]);
    if (m.v1) {
      float4* opB = (float4*)buf + 7 * (m.w2 + 11) + 3 * h;
      opB[0] = pack2(acc1[0], acc1[1]);
      opB[1] = pack2(acc1[2], acc1[3]);
      opB[2] = pack2(acc1[4], acc1[5]);
    }
  }
  if (gu3 && tid < 144) gate[tid] = pf3;  // gate buffer free now: stash gV3
  // ---- U1 on n1: task (pair p=k2*12+n2, half hh): rows (2k2)*12+n2, (2k2+1)*12+n2
  if (gu1) {
    __syncthreads();
    if (tid < 144) {
      const int p = tid >> 1, hh = tid & 1;
      const int k2 = p / 12, n2 = p - 12 * (p / 12);
#pragma unroll
      for (int n = 0; n < 6; ++n) { acc0[n] = CZERO; acc1[n] = CZERO; }
#pragma unroll
      for (int j = 0; j < 12; ++j) {
        c32 g0 = buf[ST * (j * 12 + 2 * k2) + 12];
        c32 g1 = buf[ST * (j * 12 + 2 * k2 + 1) + 12];
        const float4* ip = (const float4*)buf + 7 * (12 * j + n2) + 3 * hh;
        float4 w0 = ip[0], w1 = ip[1], w2 = ip[2];
        c32 v[6] = {C2(w0.x,w0.y), C2(w0.z,w0.w), C2(w1.x,w1.y),
                    C2(w1.z,w1.w), C2(w2.x,w2.y), C2(w2.z,w2.w)};
#pragma unroll
        for (int n = 0; n < 6; ++n) {
          acc0[n] = cfma(g0, v[n], acc0[n]);
          acc1[n] = cfma(g1, v[n], acc1[n]);
        }
      }
    }
    __syncthreads();
    if (tid < 144) {
      const int p = tid >> 1, hh = tid & 1;
      const int k2 = p / 12, n2 = p - 12 * (p / 12);
      float4* opA = (float4*)buf + 7 * ((2 * k2) * 12 + n2) + 3 * hh;
      float4* opB = (float4*)buf + 7 * ((2 * k2 + 1) * 12 + n2) + 3 * hh;
      opA[0] = pack2(acc0[0], acc0[1]); opA[1] = pack2(acc0[2], acc0[3]); opA[2] = pack2(acc0[4], acc0[5]);
      opB[0] = pack2(acc1[0], acc1[1]); opB[1] = pack2(acc1[2], acc1[3]); opB[2] = pack2(acc1[4], acc1[5]);
    }
  }
  // ---- U2 on n2: task (pair p=n1*6+k2, half hh): rows n1*12+2k2, n1*12+2k2+1
  if (gu2) {
    __syncthreads();
    if (tid < 144) {
      const int p = tid >> 1, hh = tid & 1;
      const int n1 = p / 6, k2 = p - 6 * (p / 6);
#pragma unroll
      for (int n = 0; n < 6; ++n) { acc0[n] = CZERO; acc1[n] = CZERO; }
#pragma unroll
      for (int j = 0; j < 12; ++j) {
        c32 g0 = buf[ST * (j * 12 + 2 * k2) + 13];
        c32 g1 = buf[ST * (j * 12 + 2 * k2 + 1) + 13];
        const float4* ip = (const float4*)buf + 7 * (12 * n1 + j) + 3 * hh;
        float4 w0 = ip[0], w1 = ip[1], w2 = ip[2];
        c32 v[6] = {C2(w0.x,w0.y), C2(w0.z,w0.w), C2(w1.x,w1.y),
                    C2(w1.z,w1.w), C2(w2.x,w2.y), C2(w2.z,w2.w)};
#pragma unroll
        for (int n = 0; n < 6; ++n) {
          acc0[n] = cfma(g0, v[n], acc0[n]);
          acc1[n] = cfma(g1, v[n], acc1[n]);
        }
      }
    }
    __syncthreads();
    if (tid < 144) {
      const int p = tid >> 1, hh = tid & 1;
      const int n1 = p / 6, k2 = p - 6 * (p / 6);
      float4* opA = (float4*)buf + 7 * (12 * n1 + 2 * k2) + 3 * hh;
      float4* opB = (float4*)buf + 7 * (12 * n1 + 2 * k2 + 1) + 3 * hh;
      opA[0] = pack2(acc0[0], acc0[1]); opA[1] = pack2(acc0[2], acc0[3]); opA[2] = pack2(acc0[4], acc0[5]);
      opB[0] = pack2(acc1[0], acc1[1]); opB[1] = pack2(acc1[2], acc1[3]); opB[2] = pack2(acc1[4], acc1[5]);
    }
  }
  // ---- U3 on n3: in-row; gate (broadcast reads) stashed in gate[0..143]
  if (gu3) {
    __syncthreads();
    if (tid < 144) {
      const float4* ip = (const float4*)buf + 7 * tid;
      float4 wv[6];
#pragma unroll
      for (int q = 0; q < 6; ++q) wv[q] = ip[q];
      float4* op = (float4*)buf + 7 * tid;
#pragma unroll
      for (int cpair = 0; cpair < 6; ++cpair) {
        c32 s0 = CZERO, s1 = CZERO;
#pragma unroll
        for (int j = 0; j < 12; ++j) {
          c32 v = get2(wv, j);
          s0 = cfma(gate[(2 * cpair) * 12 + j], v, s0);
          s1 = cfma(gate[(2 * cpair + 1) * 12 + j], v, s1);
        }
        op[cpair] = pack2(s0, s1);
      }
    }
  }
  __syncthreads();
  for (int v = tid; v < 864; v += 256) {
    ((float4*)slab)[v] = *((const float4*)buf + 7 * (v / 6) + (v % 6));
  }
}

// ---------------- fused pass over modes {0,1}: [init] -> U0 -> BS(0,1) ----------------
// Tile = 144 (n0,n1)-rows x 16 flat cols; in-place LDS [144][18]; pad col 16 = transposed g0v.
__global__ __launch_bounds__(256, 5) void k01_kernel(
    c32* __restrict__ psi, const c32* __restrict__ c0,
    const c32* __restrict__ gu0, const c32* __restrict__ gbs) {
  __shared__ __align__(16) c32 buf[2592];
  __shared__ c32 gate[1168];
  __shared__ c32 cv[4][12];
  const int tid = threadIdx.x;
  const int b = blockIdx.x / 9, t = blockIdx.x % 9;
  if (gu0) for (int e = tid; e < 144; e += 256) buf[KP * ((e % 12) * 12 + e / 12) + 16] = gu0[e];
  if (gbs) for (int e = tid; e < 1156; e += 256) gate[e] = gbs[e];
  c32* gbase = psi + (size_t)b * D4 + t * 16;
  if (c0) {
    if (tid < 48) cv[tid / 12][tid % 12] = c0[(size_t)b * 48 + tid];
    __syncthreads();
    for (int e = tid; e < 2304; e += 256) {
      int row = e >> 4, q = e & 15;
      int cc = 16 * t + q, n2 = cc / 12, n3 = cc - 12 * n2;
      buf[KP * row + q] =
          cmul(cmul(cv[0][row / 12], cv[1][row % 12]), cmul(cv[2][n2], cv[3][n3]));
    }
  } else {
    for (int e = tid; e < 1152; e += 256) {
      int row = e >> 3, q = e & 7;
      ((float4*)(buf + row * KP))[q] = ((const float4*)(gbase + (size_t)row * 144))[q];
    }
  }
  __syncthreads();
  c32 acc0[8], acc1[8];
  // ---- U0 on n0: task (pair p=k2*12+n1, half hh): rows (2k2)*12+n1, (2k2+1)*12+n1
  if (gu0) {
    if (tid < 144) {
      const int p = tid >> 1, hh = tid & 1;
      const int k2 = p / 12, n1 = p - 12 * (p / 12);
#pragma unroll
      for (int n = 0; n < 8; ++n) { acc0[n] = CZERO; acc1[n] = CZERO; }
#pragma unroll
      for (int j = 0; j < 12; ++j) {
        c32 g0 = buf[KP * (j * 12 + 2 * k2) + 16];
        c32 g1 = buf[KP * (j * 12 + 2 * k2 + 1) + 16];
        const float4* ip = (const float4*)(buf + (12 * j + n1) * KP) + 4 * hh;
        float4 w[4];
#pragma unroll
        for (int q = 0; q < 4; ++q) w[q] = ip[q];
#pragma unroll
        for (int n = 0; n < 8; ++n) {
          c32 v = get2(w, n);
          acc0[n] = cfma(g0, v, acc0[n]);
          acc1[n] = cfma(g1, v, acc1[n]);
        }
      }
    }
    __syncthreads();
    if (tid < 144) {
      const int p = tid >> 1, hh = tid & 1;
      const int k2 = p / 12, n1 = p - 12 * (p / 12);
      float4* opA = (float4*)(buf + ((2 * k2) * 12 + n1) * KP) + 4 * hh;
      float4* opB = (float4*)(buf + ((2 * k2 + 1) * 12 + n1) * KP) + 4 * hh;
#pragma unroll
      for (int q = 0; q < 4; ++q) {
        opA[q] = pack2(acc0[2 * q], acc0[2 * q + 1]);
        opB[q] = pack2(acc1[2 * q], acc1[2 * q + 1]);
      }
    }
    __syncthreads();
  }
  // ---- BS(0,1): pattern rows (n0,n1); (pair, 8-col-half) tasks, transposed gate walk
  if (gbs) {
    const int pr = tid >> 1, h = tid & 1;
    PM m;
    if (tid < 156) {
      m = pmeta(pr);
#pragma unroll
      for (int n = 0; n < 8; ++n) { acc0[n] = CZERO; acc1[n] = CZERO; }
      int rho = m.r0, go = m.goff;
      for (int tk = 0; tk < m.sz; ++tk) {
        c32 g0 = gate[go];
        c32 g1 = gate[go + 1];
        if (!m.v1) g1 = CZERO;
        go += m.sz;
        const float4* ip = (const float4*)(buf + rho * KP) + 4 * h;
        float4 w[4];
#pragma unroll
        for (int q = 0; q < 4; ++q) w[q] = ip[q];
#pragma unroll
        for (int n = 0; n < 8; ++n) {
          c32 v = get2(w, n);
          acc0[n] = cfma(g0, v, acc0[n]);
          acc1[n] = cfma(g1, v, acc1[n]);
        }
        rho += m.dr;
      }
    }
    __syncthreads();
    if (tid < 156) {
      float4* opA = (float4*)(buf + m.w2 * KP) + 4 * h;
#pragma unroll
      for (int q = 0; q < 4; ++q) opA[q] = pack2(acc0[2 * q], acc0[2 * q + 1]);
      if (m.v1) {
        float4* opB = (float4*)(buf + (m.w2 + 11) * KP) + 4 * h;
#pragma unroll
        for (int q = 0; q < 4; ++q) opB[q] = pack2(acc1[2 * q], acc1[2 * q + 1]);
      }
    }
    __syncthreads();
  }
  for (int e = tid; e < 1152; e += 256) {
    int row = e >> 3, q = e & 7;
    ((float4*)(gbase + (size_t)row * 144))[q] = ((const float4*)(buf + row * KP))[q];
  }
}

// ---------------- expvals: <X_m> = sum 2*sqrt(n+1)*Re(conj(psi_n) psi_{n+1}) ----------------
__global__ __launch_bounds__(256) void expval_kernel(const c32* __restrict__ psi, float* __restrict__ out) {
  __shared__ float red[1024];
  __shared__ float sq2[12];
  const int tid = threadIdx.x, b = blockIdx.x;
  if (tid < 12) sq2[tid] = 2.f * sqrtf((float)(tid + 1));
  __syncthreads();
  const c32* base = psi + (size_t)b * D4;
  float a0 = 0.f, a1 = 0.f, a2 = 0.f, a3 = 0.f;
  for (int e = tid; e < D4; e += 256) {
    c32 p = base[e];
    int n3 = e % 12, t = e / 12;
    int n2 = t % 12; t /= 12;
    int n1 = t % 12, n0 = t / 12;
    if (n3 < 11) { c32 q = base[e + 1];    a3 = fmaf(sq2[n3], fmaf(p.x, q.x, p.y * q.y), a3); }
    if (n2 < 11) { c32 q = base[e + 12];   a2 = fmaf(sq2[n2], fmaf(p.x, q.x, p.y * q.y), a2); }
    if (n1 < 11) { c32 q = base[e + 144];  a1 = fmaf(sq2[n1], fmaf(p.x, q.x, p.y * q.y), a1); }
    if (n0 < 11) { c32 q = base[e + 1728]; a0 = fmaf(sq2[n0], fmaf(p.x, q.x, p.y * q.y), a0); }
  }
  red[tid * 4 + 0] = a0; red[tid * 4 + 1] = a1; red[tid * 4 + 2] = a2; red[tid * 4 + 3] = a3;
  __syncthreads();
  for (int s = 128; s > 0; s >>= 1) {
    if (tid < s) {
      red[tid * 4 + 0] += red[(tid + s) * 4 + 0];
      red[tid * 4 + 1] += red[(tid + s) * 4 + 1];
      red[tid * 4 + 2] += red[(tid + s) * 4 + 2];
      red[tid * 4 + 3] += red[(tid + s) * 4 + 3];
    }
    __syncthreads();
  }
  if (tid < 4) out[b * 4 + tid] = red[tid];
}

extern "C" void kernel_launch(void* const* d_in, const int* in_sizes, int n_in,
                              void* d_out, int out_size, void* d_ws, size_t ws_size,
                              hipStream_t stream) {
  const float* x      = (const float*)d_in[0];
  const float* theta1 = (const float*)d_in[1];
  const float* phi1   = (const float*)d_in[2];
  const float* vphi1  = (const float*)d_in[3];
  const float* r_     = (const float*)d_in[4];
  const float* phir   = (const float*)d_in[5];
  const float* theta2 = (const float*)d_in[6];
  const float* phi2   = (const float*)d_in[7];
  const float* vphi2  = (const float*)d_in[8];
  const float* a_     = (const float*)d_in[9];
  const float* phia   = (const float*)d_in[10];
  const float* kk     = (const float*)d_in[11];
  float* out = (float*)d_out;

  // workspace layout (bytes)
  const size_t PSI_OFF = 0;                              // 1024*20736*8
  const size_t C0_OFF  = 169869312;                      // 1024*4*12*8
  const size_t P1_OFF  = C0_OFF + 393216;
  const size_t P2_OFF  = P1_OFF + 9216;
  const size_t BS_OFF  = P2_OFF + 9216;                  // 24*1156*8
  const size_t NEED    = BS_OFF + 221952;
  if (ws_size < NEED) return;

  char* ws = (char*)d_ws;
  c32* psi = (c32*)(ws + PSI_OFF);
  c32* c0  = (c32*)(ws + C0_OFF);
  c32* P1  = (c32*)(ws + P1_OFF);
  c32* P2  = (c32*)(ws + P2_OFF);
  c32* BS  = (c32*)(ws + BS_OFF);

  prep_disp<<<dim3(4096), dim3(64), 0, stream>>>(x, c0);
  prep_bs<<<dim3(552), dim3(64), 0, stream>>>(theta1, phi1, theta2, phi2, BS);
  prep_p<<<dim3(16), dim3(64), 0, stream>>>(r_, phir, vphi1, a_, phia, vphi2, kk, P1, P2);

  for (int l = 0; l < 2; ++l) {
    c32* bsl = BS + (size_t)l * 12 * 1156;
    const c32* c0arg = (l == 0) ? c0 : (const c32*)nullptr;
    const c32* u0pre = (l == 0) ? (const c32*)nullptr : (const c32*)(P2 + (size_t)(l - 1) * 4 * 144);
    // interferometer 1: Clements order (0,1),(2,3),(1,2),(0,1),(2,3),(1,2)
    k01_kernel<<<dim3(9216), dim3(256), 0, stream>>>(psi, c0arg, u0pre, bsl + 0 * 1156);
    k123_kernel<<<dim3(12288), dim3(256), 0, stream>>>(psi, bsl + 1 * 1156, bsl + 2 * 1156,
                                                       nullptr, nullptr, nullptr);
    k01_kernel<<<dim3(9216), dim3(256), 0, stream>>>(psi, nullptr, nullptr, bsl + 3 * 1156);
    k123_kernel<<<dim3(12288), dim3(256), 0, stream>>>(psi, bsl + 4 * 1156, bsl + 5 * 1156,
                                                       P1 + (size_t)(l * 4 + 1) * 144,
                                                       P1 + (size_t)(l * 4 + 2) * 144,
                                                       P1 + (size_t)(l * 4 + 3) * 144);
    // interferometer 2 (P1 mode-0 composite rides along before its first BS(0,1))
    k01_kernel<<<dim3(9216), dim3(256), 0, stream>>>(psi, nullptr, P1 + (size_t)(l * 4 + 0) * 144, bsl + 6 * 1156);
    k123_kernel<<<dim3(12288), dim3(256), 0, stream>>>(psi, bsl + 7 * 1156, bsl + 8 * 1156,
                                                       nullptr, nullptr, nullptr);
    k01_kernel<<<dim3(9216), dim3(256), 0, stream>>>(psi, nullptr, nullptr, bsl + 9 * 1156);
    k123_kernel<<<dim3(12288), dim3(256), 0, stream>>>(psi, bsl + 10 * 1156, bsl + 11 * 1156,
                                                       P2 + (size_t)(l * 4 + 1) * 144,
                                                       P2 + (size_t)(l * 4 + 2) * 144,
                                                       P2 + (size_t)(l * 4 + 3) * 144);
  }
  // final pending mode-0 composite from layer 2
  k01_kernel<<<dim3(9216), dim3(256), 0, stream>>>(psi, nullptr, P2 + (size_t)(1 * 4 + 0) * 144, nullptr);
  expval_kernel<<<dim3(1024), dim3(256), 0, stream>>>(psi, out);
}

// Round 13
// 1836.041 us; speedup vs baseline: 1.1898x; 1.0285x over previous
//
#include <hip/hip_runtime.h>
#include <math.h>

#define D4 20736
#define ST 14    // k123 LDS row stride (c32), 112B; cols 12,13 = packed gate pairs
#define SST 168  // 12*ST: spectator stride for bs23
#define KP 18    // k01 LDS row stride (c32), 144B; cols 16,17 = packed g0v pairs

typedef float c32 __attribute__((ext_vector_type(2)));

__device__ __forceinline__ c32 C2(float x, float y) { c32 r; r.x = x; r.y = y; return r; }
#define CZERO C2(0.f, 0.f)

__device__ __forceinline__ c32 cmul(c32 a, c32 b) {
  return C2(a.x * b.x - a.y * b.y, a.x * b.y + a.y * b.x);
}
// scalar complex FMA (prep kernels)
__device__ __forceinline__ c32 cfma_s(c32 a, c32 b, c32 acc) {
  acc.x = fmaf(a.x, b.x, fmaf(-a.y, b.y, acc.x));
  acc.y = fmaf(a.x, b.y, fmaf(a.y, b.x, acc.y));
  return acc;
}
// packed complex FMA: acc += g*v in 2 x v_pk_fma_f32
__device__ __forceinline__ c32 cfma(c32 g, c32 v, c32 acc) {
  c32 t, d;
  asm("v_pk_fma_f32 %0, %1, %2, %3 op_sel_hi:[0,1,1]"
      : "=v"(t) : "v"(g), "v"(v), "v"(acc));
  asm("v_pk_fma_f32 %0, %1, %2, %3 op_sel:[1,1,0] op_sel_hi:[1,0,1] neg_lo:[1,0,0]"
      : "=v"(d) : "v"(g), "v"(v), "v"(t));
  return d;
}
__device__ __forceinline__ c32 get2(const float4* w, int n) {
  float4 q = w[n >> 1];
  return (n & 1) ? C2(q.z, q.w) : C2(q.x, q.y);
}
__device__ __forceinline__ float4 pack2(c32 a, c32 b) {
  return make_float4(a.x, a.y, b.x, b.y);
}

// sector offsets: secoff[N] = sum_{n<N} sz(n)^2
__constant__ int d_secoff[24] = {0,1,5,14,30,55,91,140,204,285,385,506,650,
                                 771,871,952,1016,1065,1101,1126,1142,1151,1155,1156};

// row-PAIR tasks sorted by descending sector size; code = N*8 + k
__constant__ unsigned char d_pp[78] = {
  88,89,90,91,92,93,        // N=11 sz12
  80,81,82,83,84,85,        // N=10 sz11
  96,97,98,99,100,101,      // N=12 sz11
  72,73,74,75,76,           // N=9  sz10
  104,105,106,107,108,      // N=13 sz10
  64,65,66,67,68,           // N=8  sz9
  112,113,114,115,116,      // N=14 sz9
  56,57,58,59,              // N=7  sz8
  120,121,122,123,          // N=15 sz8
  48,49,50,51,              // N=6  sz7
  128,129,130,131,          // N=16 sz7
  40,41,42,                 // N=5  sz6
  136,137,138,              // N=17 sz6
  32,33,34,                 // N=4  sz5
  144,145,146,              // N=18 sz5
  24,25,                    // N=3  sz4
  152,153,                  // N=19 sz4
  16,17,                    // N=2  sz3
  160,161,                  // N=20 sz3
  8,                        // N=1  sz2
  168,                      // N=21 sz2
  0,                        // N=0  sz1
  176                       // N=22 sz1
};

struct PM { int sz, goff, a0, da, r0, dr, w1, w2; bool v1; };
// pair metadata. Gates transposed per sector: (p, step t) at secoff + t*sz + p;
// pair reads gate[goff], gate[goff+1]; goff += sz per step.
// One extra walk step stays in-bounds for all sectors (prefetch-safe).
__device__ __forceinline__ PM pmeta(int pr) {
  const int code = d_pp[pr];
  const int N = code >> 3, k = code & 7;
  const bool up = (N <= 11);
  PM m;
  m.sz = (up ? N : 22 - N) + 1;
  const int lo = up ? 0 : (N - 11);
  const int i0 = lo + 2 * k;
  m.v1 = (2 * k + 1 < m.sz);
  m.goff = d_secoff[N] + 2 * k;
  m.a0 = up ? N : (143 + N);
  m.da = up ? 13 : -13;
  m.r0 = up ? N : (121 + N);
  m.dr = up ? 11 : -11;
  m.w1 = 13 * i0 + N;
  m.w2 = 11 * i0 + N;
  return m;
}

// ---------------- small matrix expm (LDS, 64-thread block) ----------------
__device__ void small_expm(c32* A, c32* S, c32* P, c32* T, float* red, int sz, int tid) {
  const int n2 = sz * sz;
  if (tid < sz) {
    float s = 0.f;
    for (int j = 0; j < sz; ++j) { c32 v = A[tid * sz + j]; s += sqrtf(fmaf(v.x, v.x, v.y * v.y)); }
    red[tid] = s;
  }
  __syncthreads();
  float nrm = 0.f;
  for (int i = 0; i < sz; ++i) nrm = fmaxf(nrm, red[i]);
  int sp = 0;
  while (nrm > 0.35f && sp < 24) { nrm *= 0.5f; ++sp; }
  const float scale = ldexpf(1.f, -sp);
  for (int e = tid; e < n2; e += 64) { A[e].x *= scale; A[e].y *= scale; }
  __syncthreads();
  for (int e = tid; e < n2; e += 64) {
    c32 a = A[e];
    P[e] = a;
    if ((e / sz) == (e % sz)) a.x += 1.f;
    S[e] = a;
  }
  __syncthreads();
  for (int k = 2; k <= 12; ++k) {
    const float inv = 1.f / (float)k;
    for (int e = tid; e < n2; e += 64) {
      int i = e / sz, j = e - i * sz;
      c32 acc = CZERO;
      for (int q = 0; q < sz; ++q) acc = cfma_s(P[i * sz + q], A[q * sz + j], acc);
      acc.x *= inv; acc.y *= inv;
      T[e] = acc;
    }
    __syncthreads();
    for (int e = tid; e < n2; e += 64) {
      c32 t = T[e];
      P[e] = t;
      S[e].x += t.x; S[e].y += t.y;
    }
    __syncthreads();
  }
  for (int q = 0; q < sp; ++q) {
    for (int e = tid; e < n2; e += 64) {
      int i = e / sz, j = e - i * sz;
      c32 acc = CZERO;
      for (int w = 0; w < sz; ++w) acc = cfma_s(S[i * sz + w], S[w * sz + j], acc);
      T[e] = acc;
    }
    __syncthreads();
    for (int e = tid; e < n2; e += 64) S[e] = T[e];
    __syncthreads();
  }
}

// ---------------- prep: per-batch displacement encoding (store col 0) ----------------
__global__ __launch_bounds__(64) void prep_disp(const float* __restrict__ x, c32* __restrict__ c0) {
  __shared__ c32 A[144], S[144], P[144], T[144];
  __shared__ float red[12];
  const int tid = threadIdx.x;
  const int b = blockIdx.x >> 2, m = blockIdx.x & 3;
  const float rr = x[b * 8 + m], ph = x[b * 8 + 4 + m];
  float sn, cs;
  sincosf(ph, &sn, &cs);
  const c32 alpha = C2(rr * cs, rr * sn);
  for (int e = tid; e < 144; e += 64) A[e] = CZERO;
  __syncthreads();
  if (tid < 11) {
    float sq = sqrtf((float)(tid + 1));
    A[(tid + 1) * 12 + tid] = C2(alpha.x * sq, alpha.y * sq);
    A[tid * 12 + tid + 1] = C2(-alpha.x * sq, alpha.y * sq);
  }
  __syncthreads();
  small_expm(A, S, P, T, red, 12, tid);
  if (tid < 12) c0[(size_t)blockIdx.x * 12 + tid] = S[tid * 12];
}

// ---------------- prep: beamsplitter sector blocks (transposed, direction-arranged) ----------------
__global__ __launch_bounds__(64) void prep_bs(const float* __restrict__ th1, const float* __restrict__ ph1,
                                              const float* __restrict__ th2, const float* __restrict__ ph2,
                                              c32* __restrict__ BS) {
  __shared__ c32 A[144], S[144], P[144], T[144];
  __shared__ float red[12];
  const int tid = threadIdx.x;
  const int g = blockIdx.x / 23, N = blockIdx.x % 23;
  const int l = g / 12, rem = g % 12, w = rem / 6, gi = rem % 6;
  const float th = (w ? th2 : th1)[l * 6 + gi];
  const float ph = (w ? ph2 : ph1)[l * 6 + gi];
  const int lo = (N > 11) ? (N - 11) : 0;
  const int sz = (N <= 11) ? (N + 1) : (23 - N);
  float sn, cs;
  sincosf(ph, &sn, &cs);
  for (int e = tid; e < sz * sz; e += 64) A[e] = CZERO;
  __syncthreads();
  if (tid + 1 < sz) {
    int t = tid + 1;
    float s1 = th * sqrtf((float)((lo + t) * (N - lo - t + 1)));
    A[(t - 1) * sz + t] = C2(cs * s1, sn * s1);
    A[t * sz + t - 1] = C2(-cs * s1, sn * s1);
  }
  __syncthreads();
  small_expm(A, S, P, T, red, sz, tid);
  c32* dst = BS + (size_t)g * 1156 + d_secoff[N];
  const bool upSec = (N <= 11);
  for (int e = tid; e < sz * sz; e += 64) {
    int p = e / sz, q = e - p * sz;
    int qs = upSec ? q : (sz - 1 - q);
    dst[q * sz + p] = S[p * sz + qs];
  }
}

// ---------------- prep: per-mode composites P1 = S*R1, P2 = K*Disp*R2 ----------------
__global__ __launch_bounds__(64) void prep_p(const float* __restrict__ r_, const float* __restrict__ phir,
                                             const float* __restrict__ vphi1,
                                             const float* __restrict__ a_, const float* __restrict__ phia,
                                             const float* __restrict__ vphi2, const float* __restrict__ kk,
                                             c32* __restrict__ P1, c32* __restrict__ P2) {
  __shared__ c32 A[144], S[144], P[144], T[144];
  __shared__ float red[12];
  const int tid = threadIdx.x;
  const int which = blockIdx.x >> 3, lm = blockIdx.x & 7;
  for (int e = tid; e < 144; e += 64) A[e] = CZERO;
  __syncthreads();
  if (which == 0) {
    const float rv = r_[lm], pv = phir[lm];
    float sn, cs;
    sincosf(pv, &sn, &cs);
    const c32 z = C2(rv * cs, rv * sn);
    if (tid < 10) {
      float sq = 0.5f * sqrtf((float)((tid + 1) * (tid + 2)));
      A[tid * 12 + tid + 2] = C2(z.x * sq, -z.y * sq);
      A[(tid + 2) * 12 + tid] = C2(-z.x * sq, -z.y * sq);
    }
  } else {
    const float av = a_[lm], pv = phia[lm];
    float sn, cs;
    sincosf(pv, &sn, &cs);
    const c32 alpha = C2(av * cs, av * sn);
    if (tid < 11) {
      float sq = sqrtf((float)(tid + 1));
      A[(tid + 1) * 12 + tid] = C2(alpha.x * sq, alpha.y * sq);
      A[tid * 12 + tid + 1] = C2(-alpha.x * sq, alpha.y * sq);
    }
  }
  __syncthreads();
  small_expm(A, S, P, T, red, 12, tid);
  if (which == 0) {
    const float vp = vphi1[lm];
    for (int e = tid; e < 144; e += 64) {
      int j = e % 12;
      float sn, cs;
      sincosf(vp * (float)j, &sn, &cs);
      P1[(size_t)lm * 144 + e] = cmul(S[e], C2(cs, sn));
    }
  } else {
    const float vp = vphi2[lm], kv = kk[lm];
    for (int e = tid; e < 144; e += 64) {
      int i = e / 12, j = e % 12;
      float sn1, cs1, sn2, cs2;
      sincosf(vp * (float)j, &sn1, &cs1);
      float ang = kv * (float)i;
      ang *= (float)i;
      sincosf(ang, &sn2, &cs2);
      P2[(size_t)lm * 144 + e] = cmul(C2(cs2, sn2), cmul(S[e], C2(cs1, sn1)));
    }
  }
}

// ---------------- fused pass over modes {1,2,3}: BS(2,3) -> BS(1,2) -> U1 -> U2 -> U3 ----------------
// In-place LDS [144][14]; gate pairs for U1/U2 packed at cols 12,13 (rows 12j+k2
// for gV1, rows 12j+6+k2 for gV2) -> single b128 gate reads. BS loops 2-deep
// software-pipelined (prefetch next gate-pair + state; walks stay in-bounds).
__global__ __launch_bounds__(256, 6) void k123_kernel(
    c32* __restrict__ psi,
    const c32* __restrict__ gbs23, const c32* __restrict__ gbs12,
    const c32* __restrict__ gu1, const c32* __restrict__ gu2, const c32* __restrict__ gu3) {
  __shared__ __align__(16) c32 buf[2016];
  __shared__ c32 gate[1168];
  const int tid = threadIdx.x;
  c32 pf[5];
#pragma unroll
  for (int k = 0; k < 5; ++k) {
    int e = tid + 256 * k;
    pf[k] = (e < 1156) ? gbs12[e] : CZERO;
  }
  c32 pf3 = (gu3 && tid < 144) ? gu3[tid] : CZERO;
  // gV1/gV2 packed: element (i,j) -> row 12j+(i>>1) [+6 for gV2], col 12+(i&1)
  if (gu1) for (int e = tid; e < 144; e += 256) {
    int i = e / 12, j = e - 12 * i;
    buf[ST * (12 * j + (i >> 1)) + 12 + (i & 1)] = gu1[e];
  }
  if (gu2) for (int e = tid; e < 144; e += 256) {
    int i = e / 12, j = e - 12 * i;
    buf[ST * (12 * j + 6 + (i >> 1)) + 12 + (i & 1)] = gu2[e];
  }
  for (int e = tid; e < 1156; e += 256) gate[e] = gbs23[e];
  c32* slab = psi + (size_t)blockIdx.x * 1728;
  for (int v = tid; v < 864; v += 256) {
    float4 q = ((const float4*)slab)[v];
    *((float4*)buf + 7 * (v / 6) + (v % 6)) = q;
  }
  __syncthreads();
  const int pr = tid >> 1, h = tid & 1;
  PM m;
  if (tid < 156) m = pmeta(pr);
  c32 acc0[6], acc1[6];
  // ---- pass 1: BS(2,3), pipelined
  if (tid < 156) {
#pragma unroll
    for (int n = 0; n < 6; ++n) { acc0[n] = CZERO; acc1[n] = CZERO; }
    int a = m.a0 + 1008 * h, go = m.goff;
    c32 g0 = gate[go];
    c32 g1 = m.v1 ? gate[go + 1] : CZERO;
    c32 v[6];
#pragma unroll
    for (int n = 0; n < 6; ++n) v[n] = buf[SST * n + a];
    for (int t = 0; t < m.sz; ++t) {
      const int an = a + m.da, gon = go + m.sz;
      c32 ng0 = gate[gon];
      c32 ng1 = m.v1 ? gate[gon + 1] : CZERO;
      c32 nv[6];
#pragma unroll
      for (int n = 0; n < 6; ++n) nv[n] = buf[SST * n + an];
#pragma unroll
      for (int n = 0; n < 6; ++n) {
        acc0[n] = cfma(g0, v[n], acc0[n]);
        acc1[n] = cfma(g1, v[n], acc1[n]);
      }
      g0 = ng0; g1 = ng1;
#pragma unroll
      for (int n = 0; n < 6; ++n) v[n] = nv[n];
      a = an; go = gon;
    }
  }
  __syncthreads();
  if (tid < 156) {
    const int w0 = m.w1 + 1008 * h;
#pragma unroll
    for (int n = 0; n < 6; ++n) buf[SST * n + w0] = acc0[n];
    if (m.v1) {
#pragma unroll
      for (int n = 0; n < 6; ++n) buf[SST * n + w0 + 13] = acc1[n];
    }
  }
#pragma unroll
  for (int k = 0; k < 5; ++k) {
    int e = tid + 256 * k;
    if (e < 1156) gate[e] = pf[k];
  }
  __syncthreads();
  // ---- pass 2: BS(1,2), pipelined
  if (tid < 156) {
#pragma unroll
    for (int n = 0; n < 6; ++n) { acc0[n] = CZERO; acc1[n] = CZERO; }
    int rho = m.r0, go = m.goff;
    c32 g0 = gate[go];
    c32 g1 = m.v1 ? gate[go + 1] : CZERO;
    float4 w0, w1, w2;
    {
      const float4* ip = (const float4*)buf + 7 * rho + 3 * h;
      w0 = ip[0]; w1 = ip[1]; w2 = ip[2];
    }
    for (int t = 0; t < m.sz; ++t) {
      const int rhon = rho + m.dr, gon = go + m.sz;
      c32 ng0 = gate[gon];
      c32 ng1 = m.v1 ? gate[gon + 1] : CZERO;
      float4 nw0, nw1, nw2;
      {
        const float4* ip = (const float4*)buf + 7 * rhon + 3 * h;
        nw0 = ip[0]; nw1 = ip[1]; nw2 = ip[2];
      }
      c32 v[6] = {C2(w0.x,w0.y), C2(w0.z,w0.w), C2(w1.x,w1.y),
                  C2(w1.z,w1.w), C2(w2.x,w2.y), C2(w2.z,w2.w)};
#pragma unroll
      for (int n = 0; n < 6; ++n) {
        acc0[n] = cfma(g0, v[n], acc0[n]);
        acc1[n] = cfma(g1, v[n], acc1[n]);
      }
      g0 = ng0; g1 = ng1;
      w0 = nw0; w1 = nw1; w2 = nw2;
      rho = rhon; go = gon;
    }
  }
  __syncthreads();
  if (tid < 156) {
    float4* opA = (float4*)buf + 7 * m.w2 + 3 * h;
    opA[0] = pack2(acc0[0], acc0[1]);
    opA[1] = pack2(acc0[2], acc0[3]);
    opA[2] = pack2(acc0[4], acc0[5]);
    if (m.v1) {
      float4* opB = (float4*)buf + 7 * (m.w2 + 11) + 3 * h;
      opB[0] = pack2(acc1[0], acc1[1]);
      opB[1] = pack2(acc1[2], acc1[3]);
      opB[2] = pack2(acc1[4], acc1[5]);
    }
  }
  // stash gV3 transposed: gate[j*12+i] = gu3[i*12+j] -> (2cp,2cp+1|j) contiguous
  if (gu3 && tid < 144) gate[(tid % 12) * 12 + (tid / 12)] = pf3;
  // ---- U1 on n1: task (pair p=k2*12+n2, half hh); b128 packed gate
  if (gu1) {
    __syncthreads();
    if (tid < 144) {
      const int p = tid >> 1, hh = tid & 1;
      const int k2 = p / 12, n2 = p - 12 * (p / 12);
#pragma unroll
      for (int n = 0; n < 6; ++n) { acc0[n] = CZERO; acc1[n] = CZERO; }
#pragma unroll
      for (int j = 0; j < 12; ++j) {
        float4 gq = *((const float4*)buf + 7 * (12 * j + k2) + 6);
        c32 g0 = C2(gq.x, gq.y), g1 = C2(gq.z, gq.w);
        const float4* ip = (const float4*)buf + 7 * (12 * j + n2) + 3 * hh;
        float4 w0 = ip[0], w1 = ip[1], w2 = ip[2];
        c32 v[6] = {C2(w0.x,w0.y), C2(w0.z,w0.w), C2(w1.x,w1.y),
                    C2(w1.z,w1.w), C2(w2.x,w2.y), C2(w2.z,w2.w)};
#pragma unroll
        for (int n = 0; n < 6; ++n) {
          acc0[n] = cfma(g0, v[n], acc0[n]);
          acc1[n] = cfma(g1, v[n], acc1[n]);
        }
      }
    }
    __syncthreads();
    if (tid < 144) {
      const int p = tid >> 1, hh = tid & 1;
      const int k2 = p / 12, n2 = p - 12 * (p / 12);
      float4* opA = (float4*)buf + 7 * ((2 * k2) * 12 + n2) + 3 * hh;
      float4* opB = (float4*)buf + 7 * ((2 * k2 + 1) * 12 + n2) + 3 * hh;
      opA[0] = pack2(acc0[0], acc0[1]); opA[1] = pack2(acc0[2], acc0[3]); opA[2] = pack2(acc0[4], acc0[5]);
      opB[0] = pack2(acc1[0], acc1[1]); opB[1] = pack2(acc1[2], acc1[3]); opB[2] = pack2(acc1[4], acc1[5]);
    }
  }
  // ---- U2 on n2: task (pair p=n1*6+k2, half hh); b128 packed gate (rows +6)
  if (gu2) {
    __syncthreads();
    if (tid < 144) {
      const int p = tid >> 1, hh = tid & 1;
      const int n1 = p / 6, k2 = p - 6 * (p / 6);
#pragma unroll
      for (int n = 0; n < 6; ++n) { acc0[n] = CZERO; acc1[n] = CZERO; }
#pragma unroll
      for (int j = 0; j < 12; ++j) {
        float4 gq = *((const float4*)buf + 7 * (12 * j + 6 + k2) + 6);
        c32 g0 = C2(gq.x, gq.y), g1 = C2(gq.z, gq.w);
        const float4* ip = (const float4*)buf + 7 * (12 * n1 + j) + 3 * hh;
        float4 w0 = ip[0], w1 = ip[1], w2 = ip[2];
        c32 v[6] = {C2(w0.x,w0.y), C2(w0.z,w0.w), C2(w1.x,w1.y),
                    C2(w1.z,w1.w), C2(w2.x,w2.y), C2(w2.z,w2.w)};
#pragma unroll
        for (int n = 0; n < 6; ++n) {
          acc0[n] = cfma(g0, v[n], acc0[n]);
          acc1[n] = cfma(g1, v[n], acc1[n]);
        }
      }
    }
    __syncthreads();
    if (tid < 144) {
      const int p = tid >> 1, hh = tid & 1;
      const int n1 = p / 6, k2 = p - 6 * (p / 6);
      float4* opA = (float4*)buf + 7 * (12 * n1 + 2 * k2) + 3 * hh;
      float4* opB = (float4*)buf + 7 * (12 * n1 + 2 * k2 + 1) + 3 * hh;
      opA[0] = pack2(acc0[0], acc0[1]); opA[1] = pack2(acc0[2], acc0[3]); opA[2] = pack2(acc0[4], acc0[5]);
      opB[0] = pack2(acc1[0], acc1[1]); opB[1] = pack2(acc1[2], acc1[3]); opB[2] = pack2(acc1[4], acc1[5]);
    }
  }
  // ---- U3 on n3: in-row; transposed-stashed gate -> b128 pair reads
  if (gu3) {
    __syncthreads();
    if (tid < 144) {
      const float4* ip = (const float4*)buf + 7 * tid;
      float4 wv[6];
#pragma unroll
      for (int q = 0; q < 6; ++q) wv[q] = ip[q];
      float4* op = (float4*)buf + 7 * tid;
#pragma unroll
      for (int cpair = 0; cpair < 6; ++cpair) {
        c32 s0 = CZERO, s1 = CZERO;
#pragma unroll
        for (int j = 0; j < 12; ++j) {
          float4 gq = *((const float4*)gate + 6 * j + cpair);
          c32 v = get2(wv, j);
          s0 = cfma(C2(gq.x, gq.y), v, s0);
          s1 = cfma(C2(gq.z, gq.w), v, s1);
        }
        op[cpair] = pack2(s0, s1);
      }
    }
  }
  __syncthreads();
  for (int v = tid; v < 864; v += 256) {
    ((float4*)slab)[v] = *((const float4*)buf + 7 * (v / 6) + (v % 6));
  }
}

// ---------------- fused pass over modes {0,1}: [init] -> U0 -> BS(0,1) ----------------
// In-place LDS [144][18]; g0v pairs packed at cols 16,17; BS loop pipelined.
__global__ __launch_bounds__(256, 5) void k01_kernel(
    c32* __restrict__ psi, const c32* __restrict__ c0,
    const c32* __restrict__ gu0, const c32* __restrict__ gbs) {
  __shared__ __align__(16) c32 buf[2592];
  __shared__ c32 gate[1168];
  __shared__ c32 cv[4][12];
  const int tid = threadIdx.x;
  const int b = blockIdx.x / 9, t = blockIdx.x % 9;
  if (gu0) for (int e = tid; e < 144; e += 256) {
    int i = e / 12, j = e - 12 * i;
    buf[KP * (12 * j + (i >> 1)) + 16 + (i & 1)] = gu0[e];
  }
  if (gbs) for (int e = tid; e < 1156; e += 256) gate[e] = gbs[e];
  c32* gbase = psi + (size_t)b * D4 + t * 16;
  if (c0) {
    if (tid < 48) cv[tid / 12][tid % 12] = c0[(size_t)b * 48 + tid];
    __syncthreads();
    for (int e = tid; e < 2304; e += 256) {
      int row = e >> 4, q = e & 15;
      int cc = 16 * t + q, n2 = cc / 12, n3 = cc - 12 * n2;
      buf[KP * row + q] =
          cmul(cmul(cv[0][row / 12], cv[1][row % 12]), cmul(cv[2][n2], cv[3][n3]));
    }
  } else {
    for (int e = tid; e < 1152; e += 256) {
      int row = e >> 3, q = e & 7;
      ((float4*)(buf + row * KP))[q] = ((const float4*)(gbase + (size_t)row * 144))[q];
    }
  }
  __syncthreads();
  c32 acc0[8], acc1[8];
  // ---- U0 on n0: task (pair p=k2*12+n1, half hh); b128 packed gate
  if (gu0) {
    if (tid < 144) {
      const int p = tid >> 1, hh = tid & 1;
      const int k2 = p / 12, n1 = p - 12 * (p / 12);
#pragma unroll
      for (int n = 0; n < 8; ++n) { acc0[n] = CZERO; acc1[n] = CZERO; }
#pragma unroll
      for (int j = 0; j < 12; ++j) {
        float4 gq = *((const float4*)buf + 9 * (12 * j + k2) + 8);
        c32 g0 = C2(gq.x, gq.y), g1 = C2(gq.z, gq.w);
        const float4* ip = (const float4*)(buf + (12 * j + n1) * KP) + 4 * hh;
        float4 w[4];
#pragma unroll
        for (int q = 0; q < 4; ++q) w[q] = ip[q];
#pragma unroll
        for (int n = 0; n < 8; ++n) {
          c32 v = get2(w, n);
          acc0[n] = cfma(g0, v, acc0[n]);
          acc1[n] = cfma(g1, v, acc1[n]);
        }
      }
    }
    __syncthreads();
    if (tid < 144) {
      const int p = tid >> 1, hh = tid & 1;
      const int k2 = p / 12, n1 = p - 12 * (p / 12);
      float4* opA = (float4*)(buf + ((2 * k2) * 12 + n1) * KP) + 4 * hh;
      float4* opB = (float4*)(buf + ((2 * k2 + 1) * 12 + n1) * KP) + 4 * hh;
#pragma unroll
      for (int q = 0; q < 4; ++q) {
        opA[q] = pack2(acc0[2 * q], acc0[2 * q + 1]);
        opB[q] = pack2(acc1[2 * q], acc1[2 * q + 1]);
      }
    }
    __syncthreads();
  }
  // ---- BS(0,1): (pair, 8-col-half) tasks, pipelined
  if (gbs) {
    const int pr = tid >> 1, h = tid & 1;
    PM m;
    if (tid < 156) {
      m = pmeta(pr);
#pragma unroll
      for (int n = 0; n < 8; ++n) { acc0[n] = CZERO; acc1[n] = CZERO; }
      int rho = m.r0, go = m.goff;
      c32 g0 = gate[go];
      c32 g1 = m.v1 ? gate[go + 1] : CZERO;
      float4 w[4];
      {
        const float4* ip = (const float4*)(buf + rho * KP) + 4 * h;
#pragma unroll
        for (int q = 0; q < 4; ++q) w[q] = ip[q];
      }
      for (int tk = 0; tk < m.sz; ++tk) {
        const int rhon = rho + m.dr, gon = go + m.sz;
        c32 ng0 = gate[gon];
        c32 ng1 = m.v1 ? gate[gon + 1] : CZERO;
        float4 nw[4];
        {
          const float4* ip = (const float4*)(buf + rhon * KP) + 4 * h;
#pragma unroll
          for (int q = 0; q < 4; ++q) nw[q] = ip[q];
        }
#pragma unroll
        for (int n = 0; n < 8; ++n) {
          c32 v = get2(w, n);
          acc0[n] = cfma(g0, v, acc0[n]);
          acc1[n] = cfma(g1, v, acc1[n]);
        }
        g0 = ng0; g1 = ng1;
#pragma unroll
        for (int q = 0; q < 4; ++q) w[q] = nw[q];
        rho = rhon; go = gon;
      }
    }
    __syncthreads();
    if (tid < 156) {
      float4* opA = (float4*)(buf + m.w2 * KP) + 4 * h;
#pragma unroll
      for (int q = 0; q < 4; ++q) opA[q] = pack2(acc0[2 * q], acc0[2 * q + 1]);
      if (m.v1) {
        float4* opB = (float4*)(buf + (m.w2 + 11) * KP) + 4 * h;
#pragma unroll
        for (int q = 0; q < 4; ++q) opB[q] = pack2(acc1[2 * q], acc1[2 * q + 1]);
      }
    }
    __syncthreads();
  }
  for (int e = tid; e < 1152; e += 256) {
    int row = e >> 3, q = e & 7;
    ((float4*)(gbase + (size_t)row * 144))[q] = ((const float4*)(buf + row * KP))[q];
  }
}

// ---------------- expvals: <X_m> = sum 2*sqrt(n+1)*Re(conj(psi_n) psi_{n+1}) ----------------
__global__ __launch_bounds__(256) void expval_kernel(const c32* __restrict__ psi, float* __restrict__ out) {
  __shared__ float red[1024];
  __shared__ float sq2[12];
  const int tid = threadIdx.x, b = blockIdx.x;
  if (tid < 12) sq2[tid] = 2.f * sqrtf((float)(tid + 1));
  __syncthreads();
  const c32* base = psi + (size_t)b * D4;
  float a0 = 0.f, a1 = 0.f, a2 = 0.f, a3 = 0.f;
  for (int e = tid; e < D4; e += 256) {
    c32 p = base[e];
    int n3 = e % 12, t = e / 12;
    int n2 = t % 12; t /= 12;
    int n1 = t % 12, n0 = t / 12;
    if (n3 < 11) { c32 q = base[e + 1];    a3 = fmaf(sq2[n3], fmaf(p.x, q.x, p.y * q.y), a3); }
    if (n2 < 11) { c32 q = base[e + 12];   a2 = fmaf(sq2[n2], fmaf(p.x, q.x, p.y * q.y), a2); }
    if (n1 < 11) { c32 q = base[e + 144];  a1 = fmaf(sq2[n1], fmaf(p.x, q.x, p.y * q.y), a1); }
    if (n0 < 11) { c32 q = base[e + 1728]; a0 = fmaf(sq2[n0], fmaf(p.x, q.x, p.y * q.y), a0); }
  }
  red[tid * 4 + 0] = a0; red[tid * 4 + 1] = a1; red[tid * 4 + 2] = a2; red[tid * 4 + 3] = a3;
  __syncthreads();
  for (int s = 128; s > 0; s >>= 1) {
    if (tid < s) {
      red[tid * 4 + 0] += red[(tid + s) * 4 + 0];
      red[tid * 4 + 1] += red[(tid + s) * 4 + 1];
      red[tid * 4 + 2] += red[(tid + s) * 4 + 2];
      red[tid * 4 + 3] += red[(tid + s) * 4 + 3];
    }
    __syncthreads();
  }
  if (tid < 4) out[b * 4 + tid] = red[tid];
}

extern "C" void kernel_launch(void* const* d_in, const int* in_sizes, int n_in,
                              void* d_out, int out_size, void* d_ws, size_t ws_size,
                              hipStream_t stream) {
  const float* x      = (const float*)d_in[0];
  const float* theta1 = (const float*)d_in[1];
  const float* phi1   = (const float*)d_in[2];
  const float* vphi1  = (const float*)d_in[3];
  const float* r_     = (const float*)d_in[4];
  const float* phir   = (const float*)d_in[5];
  const float* theta2 = (const float*)d_in[6];
  const float* phi2   = (const float*)d_in[7];
  const float* vphi2  = (const float*)d_in[8];
  const float* a_     = (const float*)d_in[9];
  const float* phia   = (const float*)d_in[10];
  const float* kk     = (const float*)d_in[11];
  float* out = (float*)d_out;

  // workspace layout (bytes)
  const size_t PSI_OFF = 0;                              // 1024*20736*8
  const size_t C0_OFF  = 169869312;                      // 1024*4*12*8
  const size_t P1_OFF  = C0_OFF + 393216;
  const size_t P2_OFF  = P1_OFF + 9216;
  const size_t BS_OFF  = P2_OFF + 9216;                  // 24*1156*8
  const size_t NEED    = BS_OFF + 221952;
  if (ws_size < NEED) return;

  char* ws = (char*)d_ws;
  c32* psi = (c32*)(ws + PSI_OFF);
  c32* c0  = (c32*)(ws + C0_OFF);
  c32* P1  = (c32*)(ws + P1_OFF);
  c32* P2  = (c32*)(ws + P2_OFF);
  c32* BS  = (c32*)(ws + BS_OFF);

  prep_disp<<<dim3(4096), dim3(64), 0, stream>>>(x, c0);
  prep_bs<<<dim3(552), dim3(64), 0, stream>>>(theta1, phi1, theta2, phi2, BS);
  prep_p<<<dim3(16), dim3(64), 0, stream>>>(r_, phir, vphi1, a_, phia, vphi2, kk, P1, P2);

  for (int l = 0; l < 2; ++l) {
    c32* bsl = BS + (size_t)l * 12 * 1156;
    const c32* c0arg = (l == 0) ? c0 : (const c32*)nullptr;
    const c32* u0pre = (l == 0) ? (const c32*)nullptr : (const c32*)(P2 + (size_t)(l - 1) * 4 * 144);
    // interferometer 1: Clements order (0,1),(2,3),(1,2),(0,1),(2,3),(1,2)
    k01_kernel<<<dim3(9216), dim3(256), 0, stream>>>(psi, c0arg, u0pre, bsl + 0 * 1156);
    k123_kernel<<<dim3(12288), dim3(256), 0, stream>>>(psi, bsl + 1 * 1156, bsl + 2 * 1156,
                                                       nullptr, nullptr, nullptr);
    k01_kernel<<<dim3(9216), dim3(256), 0, stream>>>(psi, nullptr, nullptr, bsl + 3 * 1156);
    k123_kernel<<<dim3(12288), dim3(256), 0, stream>>>(psi, bsl + 4 * 1156, bsl + 5 * 1156,
                                                       P1 + (size_t)(l * 4 + 1) * 144,
                                                       P1 + (size_t)(l * 4 + 2) * 144,
                                                       P1 + (size_t)(l * 4 + 3) * 144);
    // interferometer 2 (P1 mode-0 composite rides along before its first BS(0,1))
    k01_kernel<<<dim3(9216), dim3(256), 0, stream>>>(psi, nullptr, P1 + (size_t)(l * 4 + 0) * 144, bsl + 6 * 1156);
    k123_kernel<<<dim3(12288), dim3(256), 0, stream>>>(psi, bsl + 7 * 1156, bsl + 8 * 1156,
                                                       nullptr, nullptr, nullptr);
    k01_kernel<<<dim3(9216), dim3(256), 0, stream>>>(psi, nullptr, nullptr, bsl + 9 * 1156);
    k123_kernel<<<dim3(12288), dim3(256), 0, stream>>>(psi, bsl + 10 * 1156, bsl + 11 * 1156,
                                                       P2 + (size_t)(l * 4 + 1) * 144,
                                                       P2 + (size_t)(l * 4 + 2) * 144,
                                                       P2 + (size_t)(l * 4 + 3) * 144);
  }
  // final pending mode-0 composite from layer 2
  k01_kernel<<<dim3(9216), dim3(256), 0, stream>>>(psi, nullptr, P2 + (size_t)(1 * 4 + 0) * 144, nullptr);
  expval_kernel<<<dim3(1024), dim3(256), 0, stream>>>(psi, out);
}

// Round 14
// 1778.000 us; speedup vs baseline: 1.2287x; 1.0326x over previous
//
#include <hip/hip_runtime.h>
#include <math.h>

#define D4 20736
#define ST 14    // k123 LDS row stride (c32), 112B; cols 12,13 = packed gate pairs
#define SST 168  // 12*ST: spectator stride for bs23
#define KP 18    // k01 LDS row stride (c32), 144B; cols 16,17 = packed g0v pairs

typedef float c32 __attribute__((ext_vector_type(2)));

__device__ __forceinline__ c32 C2(float x, float y) { c32 r; r.x = x; r.y = y; return r; }
#define CZERO C2(0.f, 0.f)

__device__ __forceinline__ c32 cmul(c32 a, c32 b) {
  return C2(a.x * b.x - a.y * b.y, a.x * b.y + a.y * b.x);
}
// scalar complex FMA (prep kernels)
__device__ __forceinline__ c32 cfma_s(c32 a, c32 b, c32 acc) {
  acc.x = fmaf(a.x, b.x, fmaf(-a.y, b.y, acc.x));
  acc.y = fmaf(a.x, b.y, fmaf(a.y, b.x, acc.y));
  return acc;
}
// packed complex FMA: acc += g*v in 2 x v_pk_fma_f32
__device__ __forceinline__ c32 cfma(c32 g, c32 v, c32 acc) {
  c32 t, d;
  asm("v_pk_fma_f32 %0, %1, %2, %3 op_sel_hi:[0,1,1]"
      : "=v"(t) : "v"(g), "v"(v), "v"(acc));
  asm("v_pk_fma_f32 %0, %1, %2, %3 op_sel:[1,1,0] op_sel_hi:[1,0,1] neg_lo:[1,0,0]"
      : "=v"(d) : "v"(g), "v"(v), "v"(t));
  return d;
}
__device__ __forceinline__ c32 get2(const float4* w, int n) {
  float4 q = w[n >> 1];
  return (n & 1) ? C2(q.z, q.w) : C2(q.x, q.y);
}
__device__ __forceinline__ float4 pack2(c32 a, c32 b) {
  return make_float4(a.x, a.y, b.x, b.y);
}

// sector offsets: secoff[N] = sum_{n<N} sz(n)^2
__constant__ int d_secoff[24] = {0,1,5,14,30,55,91,140,204,285,385,506,650,
                                 771,871,952,1016,1065,1101,1126,1142,1151,1155,1156};

// row-PAIR tasks sorted by descending sector size; code = N*8 + k
__constant__ unsigned char d_pp[78] = {
  88,89,90,91,92,93,        // N=11 sz12
  80,81,82,83,84,85,        // N=10 sz11
  96,97,98,99,100,101,      // N=12 sz11
  72,73,74,75,76,           // N=9  sz10
  104,105,106,107,108,      // N=13 sz10
  64,65,66,67,68,           // N=8  sz9
  112,113,114,115,116,      // N=14 sz9
  56,57,58,59,              // N=7  sz8
  120,121,122,123,          // N=15 sz8
  48,49,50,51,              // N=6  sz7
  128,129,130,131,          // N=16 sz7
  40,41,42,                 // N=5  sz6
  136,137,138,              // N=17 sz6
  32,33,34,                 // N=4  sz5
  144,145,146,              // N=18 sz5
  24,25,                    // N=3  sz4
  152,153,                  // N=19 sz4
  16,17,                    // N=2  sz3
  160,161,                  // N=20 sz3
  8,                        // N=1  sz2
  168,                      // N=21 sz2
  0,                        // N=0  sz1
  176                       // N=22 sz1
};

struct PM { int sz, goff, a0, da, r0, dr, w1, w2; bool v1; };
// pair metadata. Gates transposed per sector: (p, step t) at secoff + t*sz + p;
// pair reads gate[goff], gate[goff+1]; goff += sz per step.
// One extra walk step stays in-bounds for all sectors (prefetch-safe).
__device__ __forceinline__ PM pmeta(int pr) {
  const int code = d_pp[pr];
  const int N = code >> 3, k = code & 7;
  const bool up = (N <= 11);
  PM m;
  m.sz = (up ? N : 22 - N) + 1;
  const int lo = up ? 0 : (N - 11);
  const int i0 = lo + 2 * k;
  m.v1 = (2 * k + 1 < m.sz);
  m.goff = d_secoff[N] + 2 * k;
  m.a0 = up ? N : (143 + N);
  m.da = up ? 13 : -13;
  m.r0 = up ? N : (121 + N);
  m.dr = up ? 11 : -11;
  m.w1 = 13 * i0 + N;
  m.w2 = 11 * i0 + N;
  return m;
}

// ---------------- small matrix expm (LDS, 64-thread block) ----------------
__device__ void small_expm(c32* A, c32* S, c32* P, c32* T, float* red, int sz, int tid) {
  const int n2 = sz * sz;
  if (tid < sz) {
    float s = 0.f;
    for (int j = 0; j < sz; ++j) { c32 v = A[tid * sz + j]; s += sqrtf(fmaf(v.x, v.x, v.y * v.y)); }
    red[tid] = s;
  }
  __syncthreads();
  float nrm = 0.f;
  for (int i = 0; i < sz; ++i) nrm = fmaxf(nrm, red[i]);
  int sp = 0;
  while (nrm > 0.35f && sp < 24) { nrm *= 0.5f; ++sp; }
  const float scale = ldexpf(1.f, -sp);
  for (int e = tid; e < n2; e += 64) { A[e].x *= scale; A[e].y *= scale; }
  __syncthreads();
  for (int e = tid; e < n2; e += 64) {
    c32 a = A[e];
    P[e] = a;
    if ((e / sz) == (e % sz)) a.x += 1.f;
    S[e] = a;
  }
  __syncthreads();
  for (int k = 2; k <= 12; ++k) {
    const float inv = 1.f / (float)k;
    for (int e = tid; e < n2; e += 64) {
      int i = e / sz, j = e - i * sz;
      c32 acc = CZERO;
      for (int q = 0; q < sz; ++q) acc = cfma_s(P[i * sz + q], A[q * sz + j], acc);
      acc.x *= inv; acc.y *= inv;
      T[e] = acc;
    }
    __syncthreads();
    for (int e = tid; e < n2; e += 64) {
      c32 t = T[e];
      P[e] = t;
      S[e].x += t.x; S[e].y += t.y;
    }
    __syncthreads();
  }
  for (int q = 0; q < sp; ++q) {
    for (int e = tid; e < n2; e += 64) {
      int i = e / sz, j = e - i * sz;
      c32 acc = CZERO;
      for (int w = 0; w < sz; ++w) acc = cfma_s(S[i * sz + w], S[w * sz + j], acc);
      T[e] = acc;
    }
    __syncthreads();
    for (int e = tid; e < n2; e += 64) S[e] = T[e];
    __syncthreads();
  }
}

// ---------------- prep: per-batch displacement encoding (store col 0) ----------------
__global__ __launch_bounds__(64) void prep_disp(const float* __restrict__ x, c32* __restrict__ c0) {
  __shared__ c32 A[144], S[144], P[144], T[144];
  __shared__ float red[12];
  const int tid = threadIdx.x;
  const int b = blockIdx.x >> 2, m = blockIdx.x & 3;
  const float rr = x[b * 8 + m], ph = x[b * 8 + 4 + m];
  float sn, cs;
  sincosf(ph, &sn, &cs);
  const c32 alpha = C2(rr * cs, rr * sn);
  for (int e = tid; e < 144; e += 64) A[e] = CZERO;
  __syncthreads();
  if (tid < 11) {
    float sq = sqrtf((float)(tid + 1));
    A[(tid + 1) * 12 + tid] = C2(alpha.x * sq, alpha.y * sq);
    A[tid * 12 + tid + 1] = C2(-alpha.x * sq, alpha.y * sq);
  }
  __syncthreads();
  small_expm(A, S, P, T, red, 12, tid);
  if (tid < 12) c0[(size_t)blockIdx.x * 12 + tid] = S[tid * 12];
}

// ---------------- prep: beamsplitter sector blocks (transposed, direction-arranged) ----------------
__global__ __launch_bounds__(64) void prep_bs(const float* __restrict__ th1, const float* __restrict__ ph1,
                                              const float* __restrict__ th2, const float* __restrict__ ph2,
                                              c32* __restrict__ BS) {
  __shared__ c32 A[144], S[144], P[144], T[144];
  __shared__ float red[12];
  const int tid = threadIdx.x;
  const int g = blockIdx.x / 23, N = blockIdx.x % 23;
  const int l = g / 12, rem = g % 12, w = rem / 6, gi = rem % 6;
  const float th = (w ? th2 : th1)[l * 6 + gi];
  const float ph = (w ? ph2 : ph1)[l * 6 + gi];
  const int lo = (N > 11) ? (N - 11) : 0;
  const int sz = (N <= 11) ? (N + 1) : (23 - N);
  float sn, cs;
  sincosf(ph, &sn, &cs);
  for (int e = tid; e < sz * sz; e += 64) A[e] = CZERO;
  __syncthreads();
  if (tid + 1 < sz) {
    int t = tid + 1;
    float s1 = th * sqrtf((float)((lo + t) * (N - lo - t + 1)));
    A[(t - 1) * sz + t] = C2(cs * s1, sn * s1);
    A[t * sz + t - 1] = C2(-cs * s1, sn * s1);
  }
  __syncthreads();
  small_expm(A, S, P, T, red, sz, tid);
  c32* dst = BS + (size_t)g * 1156 + d_secoff[N];
  const bool upSec = (N <= 11);
  for (int e = tid; e < sz * sz; e += 64) {
    int p = e / sz, q = e - p * sz;
    int qs = upSec ? q : (sz - 1 - q);
    dst[q * sz + p] = S[p * sz + qs];
  }
}

// ---------------- prep: per-mode composites P1 = S*R1, P2 = K*Disp*R2 ----------------
__global__ __launch_bounds__(64) void prep_p(const float* __restrict__ r_, const float* __restrict__ phir,
                                             const float* __restrict__ vphi1,
                                             const float* __restrict__ a_, const float* __restrict__ phia,
                                             const float* __restrict__ vphi2, const float* __restrict__ kk,
                                             c32* __restrict__ P1, c32* __restrict__ P2) {
  __shared__ c32 A[144], S[144], P[144], T[144];
  __shared__ float red[12];
  const int tid = threadIdx.x;
  const int which = blockIdx.x >> 3, lm = blockIdx.x & 7;
  for (int e = tid; e < 144; e += 64) A[e] = CZERO;
  __syncthreads();
  if (which == 0) {
    const float rv = r_[lm], pv = phir[lm];
    float sn, cs;
    sincosf(pv, &sn, &cs);
    const c32 z = C2(rv * cs, rv * sn);
    if (tid < 10) {
      float sq = 0.5f * sqrtf((float)((tid + 1) * (tid + 2)));
      A[tid * 12 + tid + 2] = C2(z.x * sq, -z.y * sq);
      A[(tid + 2) * 12 + tid] = C2(-z.x * sq, -z.y * sq);
    }
  } else {
    const float av = a_[lm], pv = phia[lm];
    float sn, cs;
    sincosf(pv, &sn, &cs);
    const c32 alpha = C2(av * cs, av * sn);
    if (tid < 11) {
      float sq = sqrtf((float)(tid + 1));
      A[(tid + 1) * 12 + tid] = C2(alpha.x * sq, alpha.y * sq);
      A[tid * 12 + tid + 1] = C2(-alpha.x * sq, alpha.y * sq);
    }
  }
  __syncthreads();
  small_expm(A, S, P, T, red, 12, tid);
  if (which == 0) {
    const float vp = vphi1[lm];
    for (int e = tid; e < 144; e += 64) {
      int j = e % 12;
      float sn, cs;
      sincosf(vp * (float)j, &sn, &cs);
      P1[(size_t)lm * 144 + e] = cmul(S[e], C2(cs, sn));
    }
  } else {
    const float vp = vphi2[lm], kv = kk[lm];
    for (int e = tid; e < 144; e += 64) {
      int i = e / 12, j = e % 12;
      float sn1, cs1, sn2, cs2;
      sincosf(vp * (float)j, &sn1, &cs1);
      float ang = kv * (float)i;
      ang *= (float)i;
      sincosf(ang, &sn2, &cs2);
      P2[(size_t)lm * 144 + e] = cmul(C2(cs2, sn2), cmul(S[e], C2(cs1, sn1)));
    }
  }
}

// ---------------- fused pass over modes {1,2,3}: BS(2,3) -> BS(1,2) -> U1 -> U2 -> U3 ----------------
// In-place LDS [144][14]. BS tasks: 78 pairs x 3 spectator-chunks (234 threads);
// spectator interleave {h,h+3,h+6,h+9} keeps bank spread. U1/U2: 72 pairs x 3
// col-chunks (216 threads). Gate pairs packed at cols 12/13; gV3 in gate buffer.
__global__ __launch_bounds__(256, 6) void k123_kernel(
    c32* __restrict__ psi,
    const c32* __restrict__ gbs23, const c32* __restrict__ gbs12,
    const c32* __restrict__ gu1, const c32* __restrict__ gu2, const c32* __restrict__ gu3) {
  __shared__ __align__(16) c32 buf[2016];
  __shared__ c32 gate[1168];
  const int tid = threadIdx.x;
  c32 pf[5];
#pragma unroll
  for (int k = 0; k < 5; ++k) {
    int e = tid + 256 * k;
    pf[k] = (e < 1156) ? gbs12[e] : CZERO;
  }
  c32 pf3 = (gu3 && tid < 144) ? gu3[tid] : CZERO;
  // gV1/gV2 packed: element (i,j) -> row 12j+(i>>1) [+6 for gV2], col 12+(i&1)
  if (gu1) for (int e = tid; e < 144; e += 256) {
    int i = e / 12, j = e - 12 * i;
    buf[ST * (12 * j + (i >> 1)) + 12 + (i & 1)] = gu1[e];
  }
  if (gu2) for (int e = tid; e < 144; e += 256) {
    int i = e / 12, j = e - 12 * i;
    buf[ST * (12 * j + 6 + (i >> 1)) + 12 + (i & 1)] = gu2[e];
  }
  for (int e = tid; e < 1156; e += 256) gate[e] = gbs23[e];
  c32* slab = psi + (size_t)blockIdx.x * 1728;
  for (int v = tid; v < 864; v += 256) {
    float4 q = ((const float4*)slab)[v];
    *((float4*)buf + 7 * (v / 6) + (v % 6)) = q;
  }
  __syncthreads();
  const int pr = tid / 3, h3 = tid - 3 * (tid / 3);   // BS: 234 tasks
  PM m;
  if (tid < 234) m = pmeta(pr);
  c32 acc0[4], acc1[4];
  // ---- pass 1: BS(2,3), pipelined; spectators n1 in {h3, h3+3, h3+6, h3+9}
  if (tid < 234) {
#pragma unroll
    for (int n = 0; n < 4; ++n) { acc0[n] = CZERO; acc1[n] = CZERO; }
    const int soff = SST * h3;
    int a = m.a0, go = m.goff;
    c32 g0 = gate[go];
    c32 g1 = m.v1 ? gate[go + 1] : CZERO;
    c32 v[4];
#pragma unroll
    for (int n = 0; n < 4; ++n) v[n] = buf[soff + SST * 3 * n + a];
    for (int t = 0; t < m.sz; ++t) {
      const int an = a + m.da, gon = go + m.sz;
      c32 ng0 = gate[gon];
      c32 ng1 = m.v1 ? gate[gon + 1] : CZERO;
      c32 nv[4];
#pragma unroll
      for (int n = 0; n < 4; ++n) nv[n] = buf[soff + SST * 3 * n + an];
#pragma unroll
      for (int n = 0; n < 4; ++n) {
        acc0[n] = cfma(g0, v[n], acc0[n]);
        acc1[n] = cfma(g1, v[n], acc1[n]);
      }
      g0 = ng0; g1 = ng1;
#pragma unroll
      for (int n = 0; n < 4; ++n) v[n] = nv[n];
      a = an; go = gon;
    }
  }
  __syncthreads();
  if (tid < 234) {
    const int soff = SST * h3;
#pragma unroll
    for (int n = 0; n < 4; ++n) buf[soff + SST * 3 * n + m.w1] = acc0[n];
    if (m.v1) {
#pragma unroll
      for (int n = 0; n < 4; ++n) buf[soff + SST * 3 * n + m.w1 + 13] = acc1[n];
    }
  }
#pragma unroll
  for (int k = 0; k < 5; ++k) {
    int e = tid + 256 * k;
    if (e < 1156) gate[e] = pf[k];
  }
  __syncthreads();
  // ---- pass 2: BS(1,2), pipelined; col-chunk h3 = 2 float4 at offset 2*h3
  if (tid < 234) {
#pragma unroll
    for (int n = 0; n < 4; ++n) { acc0[n] = CZERO; acc1[n] = CZERO; }
    int rho = m.r0, go = m.goff;
    c32 g0 = gate[go];
    c32 g1 = m.v1 ? gate[go + 1] : CZERO;
    float4 w0, w1;
    {
      const float4* ip = (const float4*)buf + 7 * rho + 2 * h3;
      w0 = ip[0]; w1 = ip[1];
    }
    for (int t = 0; t < m.sz; ++t) {
      const int rhon = rho + m.dr, gon = go + m.sz;
      c32 ng0 = gate[gon];
      c32 ng1 = m.v1 ? gate[gon + 1] : CZERO;
      float4 nw0, nw1;
      {
        const float4* ip = (const float4*)buf + 7 * rhon + 2 * h3;
        nw0 = ip[0]; nw1 = ip[1];
      }
      c32 v[4] = {C2(w0.x,w0.y), C2(w0.z,w0.w), C2(w1.x,w1.y), C2(w1.z,w1.w)};
#pragma unroll
      for (int n = 0; n < 4; ++n) {
        acc0[n] = cfma(g0, v[n], acc0[n]);
        acc1[n] = cfma(g1, v[n], acc1[n]);
      }
      g0 = ng0; g1 = ng1;
      w0 = nw0; w1 = nw1;
      rho = rhon; go = gon;
    }
  }
  __syncthreads();
  if (tid < 234) {
    float4* opA = (float4*)buf + 7 * m.w2 + 2 * h3;
    opA[0] = pack2(acc0[0], acc0[1]);
    opA[1] = pack2(acc0[2], acc0[3]);
    if (m.v1) {
      float4* opB = (float4*)buf + 7 * (m.w2 + 11) + 2 * h3;
      opB[0] = pack2(acc1[0], acc1[1]);
      opB[1] = pack2(acc1[2], acc1[3]);
    }
  }
  // stash gV3 transposed: gate[j*12+i] = gu3[i*12+j] -> (2cp,2cp+1|j) contiguous
  if (gu3 && tid < 144) gate[(tid % 12) * 12 + (tid / 12)] = pf3;
  // ---- U1 on n1: 216 tasks (pair p=k2*12+n2, chunk hc)
  if (gu1) {
    __syncthreads();
    if (tid < 216) {
      const int p = tid / 3, hc = tid - 3 * (tid / 3);
      const int k2 = p / 12, n2 = p - 12 * (p / 12);
#pragma unroll
      for (int n = 0; n < 4; ++n) { acc0[n] = CZERO; acc1[n] = CZERO; }
#pragma unroll
      for (int j = 0; j < 12; ++j) {
        float4 gq = *((const float4*)buf + 7 * (12 * j + k2) + 6);
        c32 g0 = C2(gq.x, gq.y), g1 = C2(gq.z, gq.w);
        const float4* ip = (const float4*)buf + 7 * (12 * j + n2) + 2 * hc;
        float4 w0 = ip[0], w1 = ip[1];
        c32 v[4] = {C2(w0.x,w0.y), C2(w0.z,w0.w), C2(w1.x,w1.y), C2(w1.z,w1.w)};
#pragma unroll
        for (int n = 0; n < 4; ++n) {
          acc0[n] = cfma(g0, v[n], acc0[n]);
          acc1[n] = cfma(g1, v[n], acc1[n]);
        }
      }
    }
    __syncthreads();
    if (tid < 216) {
      const int p = tid / 3, hc = tid - 3 * (tid / 3);
      const int k2 = p / 12, n2 = p - 12 * (p / 12);
      float4* opA = (float4*)buf + 7 * (24 * k2 + n2) + 2 * hc;
      float4* opB = (float4*)buf + 7 * (24 * k2 + 12 + n2) + 2 * hc;
      opA[0] = pack2(acc0[0], acc0[1]); opA[1] = pack2(acc0[2], acc0[3]);
      opB[0] = pack2(acc1[0], acc1[1]); opB[1] = pack2(acc1[2], acc1[3]);
    }
  }
  // ---- U2 on n2: 216 tasks (pair p=n1*6+k2, chunk hc); packed gate rows +6
  if (gu2) {
    __syncthreads();
    if (tid < 216) {
      const int p = tid / 3, hc = tid - 3 * (tid / 3);
      const int n1 = p / 6, k2 = p - 6 * (p / 6);
#pragma unroll
      for (int n = 0; n < 4; ++n) { acc0[n] = CZERO; acc1[n] = CZERO; }
#pragma unroll
      for (int j = 0; j < 12; ++j) {
        float4 gq = *((const float4*)buf + 7 * (12 * j + 6 + k2) + 6);
        c32 g0 = C2(gq.x, gq.y), g1 = C2(gq.z, gq.w);
        const float4* ip = (const float4*)buf + 7 * (12 * n1 + j) + 2 * hc;
        float4 w0 = ip[0], w1 = ip[1];
        c32 v[4] = {C2(w0.x,w0.y), C2(w0.z,w0.w), C2(w1.x,w1.y), C2(w1.z,w1.w)};
#pragma unroll
        for (int n = 0; n < 4; ++n) {
          acc0[n] = cfma(g0, v[n], acc0[n]);
          acc1[n] = cfma(g1, v[n], acc1[n]);
        }
      }
    }
    __syncthreads();
    if (tid < 216) {
      const int p = tid / 3, hc = tid - 3 * (tid / 3);
      const int n1 = p / 6, k2 = p - 6 * (p / 6);
      float4* opA = (float4*)buf + 7 * (12 * n1 + 2 * k2) + 2 * hc;
      float4* opB = (float4*)buf + 7 * (12 * n1 + 2 * k2 + 1) + 2 * hc;
      opA[0] = pack2(acc0[0], acc0[1]); opA[1] = pack2(acc0[2], acc0[3]);
      opB[0] = pack2(acc1[0], acc1[1]); opB[1] = pack2(acc1[2], acc1[3]);
    }
  }
  // ---- U3 on n3: in-row; transposed-stashed gate -> b128 pair reads
  if (gu3) {
    __syncthreads();
    if (tid < 144) {
      const float4* ip = (const float4*)buf + 7 * tid;
      float4 wv[6];
#pragma unroll
      for (int q = 0; q < 6; ++q) wv[q] = ip[q];
      float4* op = (float4*)buf + 7 * tid;
#pragma unroll
      for (int cpair = 0; cpair < 6; ++cpair) {
        c32 s0 = CZERO, s1 = CZERO;
#pragma unroll
        for (int j = 0; j < 12; ++j) {
          float4 gq = *((const float4*)gate + 6 * j + cpair);
          c32 v = get2(wv, j);
          s0 = cfma(C2(gq.x, gq.y), v, s0);
          s1 = cfma(C2(gq.z, gq.w), v, s1);
        }
        op[cpair] = pack2(s0, s1);
      }
    }
  }
  __syncthreads();
  for (int v = tid; v < 864; v += 256) {
    ((float4*)slab)[v] = *((const float4*)buf + 7 * (v / 6) + (v % 6));
  }
}

// ---------------- fused pass over modes {0,1}: [init] -> U0 -> BS(0,1) ----------------
// In-place LDS [144][18]; g0v pairs packed at cols 16,17; BS loop pipelined.
__global__ __launch_bounds__(256, 5) void k01_kernel(
    c32* __restrict__ psi, const c32* __restrict__ c0,
    const c32* __restrict__ gu0, const c32* __restrict__ gbs) {
  __shared__ __align__(16) c32 buf[2592];
  __shared__ c32 gate[1168];
  __shared__ c32 cv[4][12];
  const int tid = threadIdx.x;
  const int b = blockIdx.x / 9, t = blockIdx.x % 9;
  if (gu0) for (int e = tid; e < 144; e += 256) {
    int i = e / 12, j = e - 12 * i;
    buf[KP * (12 * j + (i >> 1)) + 16 + (i & 1)] = gu0[e];
  }
  if (gbs) for (int e = tid; e < 1156; e += 256) gate[e] = gbs[e];
  c32* gbase = psi + (size_t)b * D4 + t * 16;
  if (c0) {
    if (tid < 48) cv[tid / 12][tid % 12] = c0[(size_t)b * 48 + tid];
    __syncthreads();
    for (int e = tid; e < 2304; e += 256) {
      int row = e >> 4, q = e & 15;
      int cc = 16 * t + q, n2 = cc / 12, n3 = cc - 12 * n2;
      buf[KP * row + q] =
          cmul(cmul(cv[0][row / 12], cv[1][row % 12]), cmul(cv[2][n2], cv[3][n3]));
    }
  } else {
    for (int e = tid; e < 1152; e += 256) {
      int row = e >> 3, q = e & 7;
      ((float4*)(buf + row * KP))[q] = ((const float4*)(gbase + (size_t)row * 144))[q];
    }
  }
  __syncthreads();
  c32 acc0[8], acc1[8];
  // ---- U0 on n0: task (pair p=k2*12+n1, half hh); b128 packed gate
  if (gu0) {
    if (tid < 144) {
      const int p = tid >> 1, hh = tid & 1;
      const int k2 = p / 12, n1 = p - 12 * (p / 12);
#pragma unroll
      for (int n = 0; n < 8; ++n) { acc0[n] = CZERO; acc1[n] = CZERO; }
#pragma unroll
      for (int j = 0; j < 12; ++j) {
        float4 gq = *((const float4*)buf + 9 * (12 * j + k2) + 8);
        c32 g0 = C2(gq.x, gq.y), g1 = C2(gq.z, gq.w);
        const float4* ip = (const float4*)(buf + (12 * j + n1) * KP) + 4 * hh;
        float4 w[4];
#pragma unroll
        for (int q = 0; q < 4; ++q) w[q] = ip[q];
#pragma unroll
        for (int n = 0; n < 8; ++n) {
          c32 v = get2(w, n);
          acc0[n] = cfma(g0, v, acc0[n]);
          acc1[n] = cfma(g1, v, acc1[n]);
        }
      }
    }
    __syncthreads();
    if (tid < 144) {
      const int p = tid >> 1, hh = tid & 1;
      const int k2 = p / 12, n1 = p - 12 * (p / 12);
      float4* opA = (float4*)(buf + ((2 * k2) * 12 + n1) * KP) + 4 * hh;
      float4* opB = (float4*)(buf + ((2 * k2 + 1) * 12 + n1) * KP) + 4 * hh;
#pragma unroll
      for (int q = 0; q < 4; ++q) {
        opA[q] = pack2(acc0[2 * q], acc0[2 * q + 1]);
        opB[q] = pack2(acc1[2 * q], acc1[2 * q + 1]);
      }
    }
    __syncthreads();
  }
  // ---- BS(0,1): (pair, 8-col-half) tasks, pipelined
  if (gbs) {
    const int pr = tid >> 1, h = tid & 1;
    PM m;
    if (tid < 156) {
      m = pmeta(pr);
#pragma unroll
      for (int n = 0; n < 8; ++n) { acc0[n] = CZERO; acc1[n] = CZERO; }
      int rho = m.r0, go = m.goff;
      c32 g0 = gate[go];
      c32 g1 = m.v1 ? gate[go + 1] : CZERO;
      float4 w[4];
      {
        const float4* ip = (const float4*)(buf + rho * KP) + 4 * h;
#pragma unroll
        for (int q = 0; q < 4; ++q) w[q] = ip[q];
      }
      for (int tk = 0; tk < m.sz; ++tk) {
        const int rhon = rho + m.dr, gon = go + m.sz;
        c32 ng0 = gate[gon];
        c32 ng1 = m.v1 ? gate[gon + 1] : CZERO;
        float4 nw[4];
        {
          const float4* ip = (const float4*)(buf + rhon * KP) + 4 * h;
#pragma unroll
          for (int q = 0; q < 4; ++q) nw[q] = ip[q];
        }
#pragma unroll
        for (int n = 0; n < 8; ++n) {
          c32 v = get2(w, n);
          acc0[n] = cfma(g0, v, acc0[n]);
          acc1[n] = cfma(g1, v, acc1[n]);
        }
        g0 = ng0; g1 = ng1;
#pragma unroll
        for (int q = 0; q < 4; ++q) w[q] = nw[q];
        rho = rhon; go = gon;
      }
    }
    __syncthreads();
    if (tid < 156) {
      float4* opA = (float4*)(buf + m.w2 * KP) + 4 * h;
#pragma unroll
      for (int q = 0; q < 4; ++q) opA[q] = pack2(acc0[2 * q], acc0[2 * q + 1]);
      if (m.v1) {
        float4* opB = (float4*)(buf + (m.w2 + 11) * KP) + 4 * h;
#pragma unroll
        for (int q = 0; q < 4; ++q) opB[q] = pack2(acc1[2 * q], acc1[2 * q + 1]);
      }
    }
    __syncthreads();
  }
  for (int e = tid; e < 1152; e += 256) {
    int row = e >> 3, q = e & 7;
    ((float4*)(gbase + (size_t)row * 144))[q] = ((const float4*)(buf + row * KP))[q];
  }
}

// ---------------- expvals: <X_m> = sum 2*sqrt(n+1)*Re(conj(psi_n) psi_{n+1}) ----------------
__global__ __launch_bounds__(256) void expval_kernel(const c32* __restrict__ psi, float* __restrict__ out) {
  __shared__ float red[1024];
  __shared__ float sq2[12];
  const int tid = threadIdx.x, b = blockIdx.x;
  if (tid < 12) sq2[tid] = 2.f * sqrtf((float)(tid + 1));
  __syncthreads();
  const c32* base = psi + (size_t)b * D4;
  float a0 = 0.f, a1 = 0.f, a2 = 0.f, a3 = 0.f;
  for (int e = tid; e < D4; e += 256) {
    c32 p = base[e];
    int n3 = e % 12, t = e / 12;
    int n2 = t % 12; t /= 12;
    int n1 = t % 12, n0 = t / 12;
    if (n3 < 11) { c32 q = base[e + 1];    a3 = fmaf(sq2[n3], fmaf(p.x, q.x, p.y * q.y), a3); }
    if (n2 < 11) { c32 q = base[e + 12];   a2 = fmaf(sq2[n2], fmaf(p.x, q.x, p.y * q.y), a2); }
    if (n1 < 11) { c32 q = base[e + 144];  a1 = fmaf(sq2[n1], fmaf(p.x, q.x, p.y * q.y), a1); }
    if (n0 < 11) { c32 q = base[e + 1728]; a0 = fmaf(sq2[n0], fmaf(p.x, q.x, p.y * q.y), a0); }
  }
  red[tid * 4 + 0] = a0; red[tid * 4 + 1] = a1; red[tid * 4 + 2] = a2; red[tid * 4 + 3] = a3;
  __syncthreads();
  for (int s = 128; s > 0; s >>= 1) {
    if (tid < s) {
      red[tid * 4 + 0] += red[(tid + s) * 4 + 0];
      red[tid * 4 + 1] += red[(tid + s) * 4 + 1];
      red[tid * 4 + 2] += red[(tid + s) * 4 + 2];
      red[tid * 4 + 3] += red[(tid + s) * 4 + 3];
    }
    __syncthreads();
  }
  if (tid < 4) out[b * 4 + tid] = red[tid];
}

extern "C" void kernel_launch(void* const* d_in, const int* in_sizes, int n_in,
                              void* d_out, int out_size, void* d_ws, size_t ws_size,
                              hipStream_t stream) {
  const float* x      = (const float*)d_in[0];
  const float* theta1 = (const float*)d_in[1];
  const float* phi1   = (const float*)d_in[2];
  const float* vphi1  = (const float*)d_in[3];
  const float* r_     = (const float*)d_in[4];
  const float* phir   = (const float*)d_in[5];
  const float* theta2 = (const float*)d_in[6];
  const float* phi2   = (const float*)d_in[7];
  const float* vphi2  = (const float*)d_in[8];
  const float* a_     = (const float*)d_in[9];
  const float* phia   = (const float*)d_in[10];
  const float* kk     = (const float*)d_in[11];
  float* out = (float*)d_out;

  // workspace layout (bytes)
  const size_t PSI_OFF = 0;                              // 1024*20736*8
  const size_t C0_OFF  = 169869312;                      // 1024*4*12*8
  const size_t P1_OFF  = C0_OFF + 393216;
  const size_t P2_OFF  = P1_OFF + 9216;
  const size_t BS_OFF  = P2_OFF + 9216;                  // 24*1156*8
  const size_t NEED    = BS_OFF + 221952;
  if (ws_size < NEED) return;

  char* ws = (char*)d_ws;
  c32* psi = (c32*)(ws + PSI_OFF);
  c32* c0  = (c32*)(ws + C0_OFF);
  c32* P1  = (c32*)(ws + P1_OFF);
  c32* P2  = (c32*)(ws + P2_OFF);
  c32* BS  = (c32*)(ws + BS_OFF);

  prep_disp<<<dim3(4096), dim3(64), 0, stream>>>(x, c0);
  prep_bs<<<dim3(552), dim3(64), 0, stream>>>(theta1, phi1, theta2, phi2, BS);
  prep_p<<<dim3(16), dim3(64), 0, stream>>>(r_, phir, vphi1, a_, phia, vphi2, kk, P1, P2);

  for (int l = 0; l < 2; ++l) {
    c32* bsl = BS + (size_t)l * 12 * 1156;
    const c32* c0arg = (l == 0) ? c0 : (const c32*)nullptr;
    const c32* u0pre = (l == 0) ? (const c32*)nullptr : (const c32*)(P2 + (size_t)(l - 1) * 4 * 144);
    // interferometer 1: Clements order (0,1),(2,3),(1,2),(0,1),(2,3),(1,2)
    k01_kernel<<<dim3(9216), dim3(256), 0, stream>>>(psi, c0arg, u0pre, bsl + 0 * 1156);
    k123_kernel<<<dim3(12288), dim3(256), 0, stream>>>(psi, bsl + 1 * 1156, bsl + 2 * 1156,
                                                       nullptr, nullptr, nullptr);
    k01_kernel<<<dim3(9216), dim3(256), 0, stream>>>(psi, nullptr, nullptr, bsl + 3 * 1156);
    k123_kernel<<<dim3(12288), dim3(256), 0, stream>>>(psi, bsl + 4 * 1156, bsl + 5 * 1156,
                                                       P1 + (size_t)(l * 4 + 1) * 144,
                                                       P1 + (size_t)(l * 4 + 2) * 144,
                                                       P1 + (size_t)(l * 4 + 3) * 144);
    // interferometer 2 (P1 mode-0 composite rides along before its first BS(0,1))
    k01_kernel<<<dim3(9216), dim3(256), 0, stream>>>(psi, nullptr, P1 + (size_t)(l * 4 + 0) * 144, bsl + 6 * 1156);
    k123_kernel<<<dim3(12288), dim3(256), 0, stream>>>(psi, bsl + 7 * 1156, bsl + 8 * 1156,
                                                       nullptr, nullptr, nullptr);
    k01_kernel<<<dim3(9216), dim3(256), 0, stream>>>(psi, nullptr, nullptr, bsl + 9 * 1156);
    k123_kernel<<<dim3(12288), dim3(256), 0, stream>>>(psi, bsl + 10 * 1156, bsl + 11 * 1156,
                                                       P2 + (size_t)(l * 4 + 1) * 144,
                                                       P2 + (size_t)(l * 4 + 2) * 144,
                                                       P2 + (size_t)(l * 4 + 3) * 144);
  }
  // final pending mode-0 composite from layer 2
  k01_kernel<<<dim3(9216), dim3(256), 0, stream>>>(psi, nullptr, P2 + (size_t)(1 * 4 + 0) * 144, nullptr);
  expval_kernel<<<dim3(1024), dim3(256), 0, stream>>>(psi, out);
}